// Round 7
// baseline (1878.587 us; speedup 1.0000x reference)
//
#include <hip/hip_runtime.h>
#include <cstddef>
#include <cstdint>

#define DIVUP(a,b) (((a)+(b)-1)/(b))

typedef __attribute__((ext_vector_type(8))) short short8;
typedef __attribute__((ext_vector_type(4))) float f32x4;

__device__ __forceinline__ ushort f2bf(float f) {
    union { float f; uint32_t u; } v; v.f = f;
    uint32_t r = v.u + 0x7fffu + ((v.u >> 16) & 1u);
    return (ushort)(r >> 16);
}

// ======================= fp32 direct conv (Cin=1 stride-2 encoder) + fused stats ====
template<int COUT, int STRIDE>
__global__ __launch_bounds__(256)
void conv3x3_k(const float* __restrict__ in, const float* __restrict__ wgt,
               const float* __restrict__ bias, float* __restrict__ out,
               float* __restrict__ stats, int Cin, int D, int H, int W)
{
    constexpr int TD = 4, TH = 8, TW = 8;
    constexpr int ID = (STRIDE == 1) ? TD + 2 : 2 * TD + 1;
    constexpr int IH = (STRIDE == 1) ? TH + 2 : 2 * TH + 1;
    constexpr int IW = (STRIDE == 1) ? TW + 2 : 2 * TW + 1;
    __shared__ float tile[ID * IH * IW];
    const int Do = D / STRIDE, Ho = H / STRIDE, Wo = W / STRIDE;
    const int tid = threadIdx.x;
    const int tw = tid & 7, th = (tid >> 3) & 7, td = tid >> 6;
    const int ow0 = blockIdx.x * TW, oh0 = blockIdx.y * TH, od0 = blockIdx.z * TD;
    const int iw0 = ow0 * STRIDE - 1, ih0 = oh0 * STRIDE - 1, id0 = od0 * STRIDE - 1;
    const size_t HWs = (size_t)H * W;

    float acc[COUT];
#pragma unroll
    for (int i = 0; i < COUT; i++) acc[i] = 0.f;

    for (int c = 0; c < Cin; ++c) {
        const float* inc = in + (size_t)c * D * HWs;
        for (int i = tid; i < ID * IH * IW; i += 256) {
            int lw = i % IW, lh = (i / IW) % IH, ld = i / (IW * IH);
            int gw = iw0 + lw, gh = ih0 + lh, gd = id0 + ld;
            float v = 0.f;
            if ((unsigned)gw < (unsigned)W && (unsigned)gh < (unsigned)H &&
                (unsigned)gd < (unsigned)D)
                v = inc[(size_t)gd * HWs + (size_t)gh * W + gw];
            tile[i] = v;
        }
        __syncthreads();
        float r[27];
        const int bd = td * STRIDE, bh = th * STRIDE, bw = tw * STRIDE;
#pragma unroll
        for (int kd = 0; kd < 3; kd++)
#pragma unroll
            for (int kh = 0; kh < 3; kh++)
#pragma unroll
                for (int kw = 0; kw < 3; kw++)
                    r[kd * 9 + kh * 3 + kw] =
                        tile[(bd + kd) * (IH * IW) + (bh + kh) * IW + (bw + kw)];
#pragma unroll
        for (int oc = 0; oc < COUT; ++oc) {
            const float* wp = wgt + ((size_t)oc * Cin + c) * 27;
            float s = 0.f;
#pragma unroll
            for (int t = 0; t < 27; t++) s = fmaf(wp[t], r[t], s);
            acc[oc] += s;
        }
        __syncthreads();
    }
    const size_t So = (size_t)Do * Ho * Wo;
    const size_t sp = (size_t)(od0 + td) * Ho * Wo + (size_t)(oh0 + th) * Wo + (ow0 + tw);
#pragma unroll
    for (int oc = 0; oc < COUT; ++oc)
        out[(size_t)oc * So + sp] = acc[oc] + bias[oc];

    if (stats) {
        __syncthreads();
        float* sm = tile;
        const int wv = tid >> 6, l = tid & 63;
#pragma unroll
        for (int oc = 0; oc < COUT; ++oc) {
            float sv = acc[oc] + bias[oc];
            float sq = sv * sv;
#pragma unroll
            for (int o = 32; o > 0; o >>= 1) {
                sv += __shfl_down(sv, o, 64);
                sq += __shfl_down(sq, o, 64);
            }
            if (l == 0) { sm[(wv * COUT + oc) * 2] = sv; sm[(wv * COUT + oc) * 2 + 1] = sq; }
        }
        __syncthreads();
        if (tid < COUT) {
            float s = 0.f, s2 = 0.f;
#pragma unroll
            for (int w = 0; w < 4; ++w) {
                s += sm[(w * COUT + tid) * 2];
                s2 += sm[(w * COUT + tid) * 2 + 1];
            }
            atomicAdd(&stats[2 * tid], s);
            atomicAdd(&stats[2 * tid + 1], s2);
        }
    }
}

// ======================= MFMA implicit-GEMM conv (TH=8, fused stats, opt split-K) ===
// nz = z-tiles in grid.z; split = blockIdx.z/nz picks K-range [split*splitpt, +splitpt)
// and output buffer (outcf vs part1). splitpt==0 -> no split.
template<int CP, int NF, int STRIDE, int MW, int COUTR, int TH>
__global__ __launch_bounds__(MW * 64)
void mconv_k(const ushort* __restrict__ xcl, const ushort* __restrict__ wp,
             const float* __restrict__ bias, float* __restrict__ outcf,
             float* __restrict__ part1, float* __restrict__ stats,
             int D, int H, int W, int nz, int splitpt)
{
    constexpr int KC = CP / 32;
    constexpr int MF = (STRIDE == 1) ? TH / 2 : 1;
    constexpr int TD = MW;
    constexpr int TWl = (STRIDE == 1) ? 8 : 4;
    constexpr int HD = (STRIDE == 1) ? TD + 2 : 2 * TD + 1;
    constexpr int HH = (STRIDE == 1) ? TH + 2 : 9;
    constexpr int HWd = (STRIDE == 1) ? 10 : 9;
    constexpr int HALO = HD * HH * HWd;
    constexpr int NTH = MW * 64;
    constexpr int NIT = (HALO * 4 + NTH - 1) / NTH;
    __shared__ __align__(16) ushort lds[HALO * 40];

    const int tid = threadIdx.x;
    const int wv = tid >> 6, l = tid & 63;
    const int zb = (int)blockIdx.z % nz, sp = (int)blockIdx.z / nz;
    const int kc0 = sp * splitpt;
    const int kc1 = (splitpt == 0) ? KC : min(KC, kc0 + splitpt);
    float* outp = sp ? part1 : outcf;
    const int od0 = zb * TD, oh0 = blockIdx.y * ((STRIDE == 1) ? TH : 4),
              ow0 = blockIdx.x * TWl;
    const int id0 = od0 * STRIDE - 1, ih0 = oh0 * STRIDE - 1, iw0 = ow0 * STRIDE - 1;

    f32x4 acc[MF][NF];
#pragma unroll
    for (int mf = 0; mf < MF; mf++)
#pragma unroll
        for (int nf = 0; nf < NF; nf++) acc[mf][nf] = f32x4{0.f, 0.f, 0.f, 0.f};

    uint4 v[NIT];
    auto stage = [&](int kc) {
#pragma unroll
        for (int it = 0; it < NIT; ++it) {
            int idx = it * NTH + tid;
            uint4 t = {0u, 0u, 0u, 0u};
            if (idx < HALO * 4) {
                int pt = idx >> 2, part = idx & 3;
                int lw = pt % HWd, lh = (pt / HWd) % HH, ld = pt / (HWd * HH);
                int gx = iw0 + lw, gy = ih0 + lh, gz = id0 + ld;
                if ((unsigned)gx < (unsigned)W && (unsigned)gy < (unsigned)H &&
                    (unsigned)gz < (unsigned)D)
                    t = *reinterpret_cast<const uint4*>(
                        xcl + ((size_t)((gz * H + gy) * W + gx)) * CP + kc * 32 + part * 8);
            }
            v[it] = t;
        }
    };

    stage(kc0);
    for (int kc = kc0; kc < kc1; ++kc) {
        if (kc > kc0) __syncthreads();
#pragma unroll
        for (int it = 0; it < NIT; ++it) {
            int idx = it * NTH + tid;
            if (idx < HALO * 4)
                *reinterpret_cast<uint4*>(&lds[(idx >> 2) * 40 + (idx & 3) * 8]) = v[it];
        }
        __syncthreads();
        if (kc + 1 < kc1) stage(kc + 1);
        if constexpr (STRIDE == 1) {
#pragma unroll
            for (int kd = 0; kd < 3; ++kd) {
#pragma unroll
                for (int kw = 0; kw < 3; ++kw) {
                    short8 af[2 * MF + 1];
#pragma unroll
                    for (int r = 0; r < 2 * MF + 1; ++r)
                        af[r] = *reinterpret_cast<const short8*>(
                            &lds[((wv + kd) * (HH * HWd) +
                                  (r + ((l >> 3) & 1)) * HWd + (l & 7) + kw) * 40 +
                                 ((l >> 4) << 3)]);
#pragma unroll
                    for (int kh = 0; kh < 3; ++kh) {
                        const int t = kd * 9 + kh * 3 + kw;
                        short8 bf[NF];
#pragma unroll
                        for (int nf = 0; nf < NF; ++nf)
                            bf[nf] = *reinterpret_cast<const short8*>(
                                wp + (((size_t)(t * KC + kc) * NF + nf) << 9) + (l << 3));
#pragma unroll
                        for (int mf = 0; mf < MF; ++mf)
#pragma unroll
                            for (int nf = 0; nf < NF; ++nf)
                                acc[mf][nf] = __builtin_amdgcn_mfma_f32_16x16x32_bf16(
                                    af[2 * mf + kh], bf[nf], acc[mf][nf], 0, 0, 0);
                    }
                }
            }
        } else {
#pragma unroll
            for (int t = 0; t < 27; ++t) {
                const int kd = t / 9, kh = (t / 3) % 3, kw = t % 3;
                short8 bf[NF];
#pragma unroll
                for (int nf = 0; nf < NF; ++nf)
                    bf[nf] = *reinterpret_cast<const short8*>(
                        wp + (((size_t)(t * KC + kc) * NF + nf) << 9) + (l << 3));
                int bw = l & 3, bh = (l >> 2) & 3;
                int p_loc = (2 * wv + kd) * (HH * HWd) + (2 * bh + kh) * HWd + (2 * bw + kw);
                short8 afs = *reinterpret_cast<const short8*>(&lds[p_loc * 40 + ((l >> 4) << 3)]);
#pragma unroll
                for (int nf = 0; nf < NF; ++nf)
                    acc[0][nf] = __builtin_amdgcn_mfma_f32_16x16x32_bf16(
                        afs, bf[nf], acc[0][nf], 0, 0, 0);
            }
        }
    }
    const int Do = D / STRIDE, Ho = H / STRIDE, Wo = W / STRIDE;
    const size_t So = (size_t)Do * Ho * Wo;
    float ps[NF], ps2[NF];
#pragma unroll
    for (int nf = 0; nf < NF; ++nf) { ps[nf] = 0.f; ps2[nf] = 0.f; }
#pragma unroll
    for (int nf = 0; nf < NF; ++nf) {
        int oc = nf * 16 + (l & 15);
        float bv = (bias && oc < COUTR) ? bias[oc] : 0.f;
#pragma unroll
        for (int mf = 0; mf < MF; ++mf) {
#pragma unroll
            for (int r = 0; r < 4; ++r) {
                int q = ((l >> 4) << 2) + r;
                int bw, bh;
                if (STRIDE == 1) { bw = q & 7; bh = 2 * mf + (q >> 3); }
                else             { bw = q & 3; bh = (q >> 2) & 3; }
                int p = ((od0 + wv) * Ho + (oh0 + bh)) * Wo + (ow0 + bw);
                float val = acc[mf][nf][r] + bv;
                if (oc < COUTR) {
                    outp[(size_t)oc * So + p] = val;
                    ps[nf] += val; ps2[nf] = fmaf(val, val, ps2[nf]);
                }
            }
        }
    }
    if (stats) {
        __syncthreads();
        float* sm = (float*)lds;
#pragma unroll
        for (int nf = 0; nf < NF; ++nf) {
            float s = ps[nf], s2 = ps2[nf];
            s += __shfl_down(s, 32, 64);  s2 += __shfl_down(s2, 32, 64);
            s += __shfl_down(s, 16, 64);  s2 += __shfl_down(s2, 16, 64);
            if (l < 16) {
                sm[((wv * NF + nf) * 16 + l) * 2] = s;
                sm[((wv * NF + nf) * 16 + l) * 2 + 1] = s2;
            }
        }
        __syncthreads();
        if (tid < NF * 16) {
            int nf = tid >> 4, c = tid & 15, oc = nf * 16 + c;
            if (oc < COUTR) {
                float s = 0.f, s2 = 0.f;
#pragma unroll
                for (int w = 0; w < MW; ++w) {
                    s += sm[((w * NF + nf) * 16 + c) * 2];
                    s2 += sm[((w * NF + nf) * 16 + c) * 2 + 1];
                }
                atomicAdd(&stats[2 * oc], s);
                atomicAdd(&stats[2 * oc + 1], s2);
            }
        }
    }
}

// ======================= split-K reduce: out = p0+p1+bias, fused stats ==============
__global__ __launch_bounds__(256)
void sumred_k(const float* __restrict__ p0, const float* __restrict__ p1,
              const float* __restrict__ bias, float* __restrict__ out,
              float* __restrict__ stats, size_t S)
{
    int c = blockIdx.y;
    size_t i = (size_t)blockIdx.x * 256 + threadIdx.x;
    float val = 0.f;
    if (i < S) {
        val = p0[(size_t)c * S + i] + p1[(size_t)c * S + i] + bias[c];
        out[(size_t)c * S + i] = val;
    }
    float s = val, s2 = val * val;
#pragma unroll
    for (int o = 32; o > 0; o >>= 1) { s += __shfl_down(s, o, 64); s2 += __shfl_down(s2, o, 64); }
    __shared__ float bs[4], bs2[4];
    int wv = threadIdx.x >> 6;
    if ((threadIdx.x & 63) == 0) { bs[wv] = s; bs2[wv] = s2; }
    __syncthreads();
    if (threadIdx.x == 0) {
        atomicAdd(&stats[2 * c], bs[0] + bs[1] + bs[2] + bs[3]);
        atomicAdd(&stats[2 * c + 1], bs2[0] + bs2[1] + bs2[2] + bs2[3]);
    }
}

// ======================= consolidated weight prep ============================
struct WTask { const float* src; void* dst; int kind, Cin, COUT, KC, coutr, base; };
struct WTab { WTask t[17]; int n; };

__global__ __launch_bounds__(256)
void wprep_k(WTab tab)
{
    int b = blockIdx.x, ti = 0;
    for (int i = 0; i < tab.n; ++i) if (b >= tab.t[i].base) ti = i;
    const WTask tk = tab.t[ti];
    int idx = (b - tk.base) * 256 + threadIdx.x;
    if (tk.kind == 0) {
        int NF = tk.COUT >> 4;
        int tot = 27 * tk.KC * NF * 512;
        if (idx >= tot) return;
        int j = idx & 7, l = (idx >> 3) & 63;
        int g = idx >> 9;
        int nf = g % NF; g /= NF;
        int kc = g % tk.KC; int t = g / tk.KC;
        int oc = nf * 16 + (l & 15);
        int c = kc * 32 + ((l >> 4) << 3) + j;
        float v = (c < tk.Cin && oc < tk.coutr)
                      ? tk.src[((size_t)oc * tk.Cin + c) * 27 + t] : 0.f;
        ((ushort*)tk.dst)[idx] = f2bf(v);
    } else if (tk.kind == 1) {
        int NF = tk.KC;
        int tot = 8 * 8 * NF * 512;
        if (idx >= tot) return;
        int j = idx & 7, l = (idx >> 3) & 63;
        int g = idx >> 9;
        int nf = g % NF; g /= NF;
        int t = g % 8; int pp = g / 8;
        int oc = nf * 16 + (l & 15);
        int c = ((l >> 4) << 3) + j;
        int kd_ = (t >> 2) & 1, kh_ = (t >> 1) & 1, kw_ = t & 1;
        int pd = (pp >> 2) & 1, ph = (pp >> 1) & 1, pw = pp & 1;
        int kd = 3 - pd - 2 * kd_, kh = 3 - ph - 2 * kh_, kw = 3 - pw - 2 * kw_;
        float v = (oc < tk.COUT)
                      ? tk.src[(size_t)(c * tk.COUT + oc) * 64 + kd * 16 + kh * 4 + kw] : 0.f;
        ((ushort*)tk.dst)[idx] = f2bf(v);
    } else {
        int tot = tk.Cin * tk.COUT * 64;
        if (idx >= tot) return;
        int k = idx & 63; int oc = (idx >> 6) % tk.COUT; int c = (idx >> 6) / tk.COUT;
        ((float*)tk.dst)[((size_t)c * 64 + k) * tk.COUT + oc] = tk.src[idx];
    }
}

// ======================= MFMA deconv (uf1) =======================
template<int NF>
__global__ __launch_bounds__(256)
void mdeconv_k(const ushort* __restrict__ xcl, const ushort* __restrict__ wpd,
               const float* __restrict__ bias, ushort* __restrict__ outcl,
               int c0, int CPo, int Si)
{
    constexpr int HD = 5, HH = 9, HWd = 9, HALO = HD * HH * HWd;
    __shared__ __align__(16) ushort lds[HALO * 40];
    const int tid = threadIdx.x, wv = tid >> 6, l = tid & 63;
    const int pp = blockIdx.z & 7, tz = blockIdx.z >> 3;
    const int pd = (pp >> 2) & 1, ph = (pp >> 1) & 1, pw = pp & 1;
    const int oz0 = tz * 4, oy0 = blockIdx.y * 8, ox0 = blockIdx.x * 8;
    const int iz0 = oz0 + pd - 1, iy0 = oy0 + ph - 1, ix0 = ox0 + pw - 1;

    for (int idx = tid; idx < HALO * 4; idx += 256) {
        int pt = idx >> 2, part = idx & 3;
        int lw = pt % HWd, lh = (pt / HWd) % HH, ld = pt / (HWd * HH);
        int gx = ix0 + lw, gy = iy0 + lh, gz = iz0 + ld;
        uint4 t = {0u, 0u, 0u, 0u};
        if ((unsigned)gx < (unsigned)Si && (unsigned)gy < (unsigned)Si &&
            (unsigned)gz < (unsigned)Si)
            t = *reinterpret_cast<const uint4*>(
                xcl + ((size_t)((gz * Si + gy) * Si + gx)) * 32 + part * 8);
        *reinterpret_cast<uint4*>(&lds[pt * 40 + part * 8]) = t;
    }
    __syncthreads();

    f32x4 acc[4][NF];
#pragma unroll
    for (int mf = 0; mf < 4; mf++)
#pragma unroll
        for (int nf = 0; nf < NF; nf++) acc[mf][nf] = f32x4{0.f, 0.f, 0.f, 0.f};

#pragma unroll
    for (int kd = 0; kd < 2; ++kd) {
#pragma unroll
        for (int kw = 0; kw < 2; ++kw) {
            short8 af[8];
#pragma unroll
            for (int r = 0; r < 8; ++r)
                af[r] = *reinterpret_cast<const short8*>(
                    &lds[((wv + kd) * (HH * HWd) + (r + ((l >> 3) & 1)) * HWd +
                          (l & 7) + kw) * 40 + ((l >> 4) << 3)]);
#pragma unroll
            for (int kh = 0; kh < 2; ++kh) {
                const int t = kd * 4 + kh * 2 + kw;
                short8 bf[NF];
#pragma unroll
                for (int nf = 0; nf < NF; ++nf)
                    bf[nf] = *reinterpret_cast<const short8*>(
                        wpd + (((size_t)(pp * 8 + t) * NF + nf) << 9) + (l << 3));
#pragma unroll
                for (int mf = 0; mf < 4; ++mf)
#pragma unroll
                    for (int nf = 0; nf < NF; ++nf)
                        acc[mf][nf] = __builtin_amdgcn_mfma_f32_16x16x32_bf16(
                            af[2 * mf + kh], bf[nf], acc[mf][nf], 0, 0, 0);
            }
        }
    }
    const int Do = 2 * Si;
#pragma unroll
    for (int nf = 0; nf < NF; ++nf) {
        int oc = nf * 16 + (l & 15);
        float bv = bias[oc];
#pragma unroll
        for (int mf = 0; mf < 4; ++mf) {
#pragma unroll
            for (int r = 0; r < 4; ++r) {
                int q = ((l >> 4) << 2) + r;
                int bw = q & 7, bh = 2 * mf + (q >> 3);
                int oD = 2 * (oz0 + wv) + pd, oH = 2 * (oy0 + bh) + ph, oW = 2 * (ox0 + bw) + pw;
                outcl[(size_t)((oD * Do + oH) * Do + oW) * CPo + c0 + oc] =
                    f2bf(acc[mf][nf][r] + bv);
            }
        }
    }
}

// ======================= output-centric small deconv (COUT=3) ====
template<int CIN>
__global__ __launch_bounds__(256)
void dctn_k(const float* __restrict__ in, const float* __restrict__ wt,
            const float* __restrict__ bias, float* __restrict__ outcf,
            ushort* __restrict__ outcl, int c0, int CPo, int Si)
{
    const int Do = 2 * Si;
    const size_t So = (size_t)Do * Do * Do, ni = (size_t)Si * Si * Si;
    size_t p = (size_t)blockIdx.x * 256 + threadIdx.x;
    if (p >= So) return;
    int oxW = (int)(p % Do), oyH = (int)((p / Do) % Do), ozD = (int)(p / ((size_t)Do * Do));
    int pw = oxW & 1, ph = oyH & 1, pd = ozD & 1;
    int xb = oxW >> 1, yb = oyH >> 1, zb = ozD >> 1;
    float acc[3] = {0.f, 0.f, 0.f};
    for (int c = 0; c < CIN; ++c) {
        const float* inc = in + (size_t)c * ni;
        const float* wc = wt + (size_t)c * 64 * 3;
#pragma unroll
        for (int jd = 0; jd < 2; jd++) {
            int iz = zb + pd - jd; if ((unsigned)iz >= (unsigned)Si) continue;
            int kd = 1 - pd + 2 * jd;
#pragma unroll
            for (int jh = 0; jh < 2; jh++) {
                int iy = yb + ph - jh; if ((unsigned)iy >= (unsigned)Si) continue;
                int kh = 1 - ph + 2 * jh;
#pragma unroll
                for (int jw = 0; jw < 2; jw++) {
                    int ix = xb + pw - jw; if ((unsigned)ix >= (unsigned)Si) continue;
                    int kw = 1 - pw + 2 * jw;
                    float v = inc[((size_t)iz * Si + iy) * Si + ix];
                    const float* wr = wc + (size_t)((kd * 4 + kh) * 4 + kw) * 3;
                    acc[0] = fmaf(wr[0], v, acc[0]);
                    acc[1] = fmaf(wr[1], v, acc[1]);
                    acc[2] = fmaf(wr[2], v, acc[2]);
                }
            }
        }
    }
#pragma unroll
    for (int oc = 0; oc < 3; ++oc) {
        float o = acc[oc] + bias[oc];
        if (outcf) outcf[(size_t)oc * So + p] = o;
        if (outcl) outcl[p * CPo + c0 + oc] = f2bf(o);
    }
}

// ======================= instance norm apply =======================
__global__ __launch_bounds__(256)
void inorm_apply_k(const float* __restrict__ x, const float* __restrict__ stats,
                   float* __restrict__ y, size_t S, float invS,
                   ushort* __restrict__ ycl, int CP)
{
    int c = blockIdx.y;
    float sum = stats[2 * c], ss = stats[2 * c + 1];
    float m = sum * invS;
    float r = rsqrtf(fmaxf(ss * invS - m * m, 0.f) + 1e-5f);
    size_t i = (size_t)blockIdx.x * 256 + threadIdx.x;
    if (i >= S) return;
    float v = (x[(size_t)c * S + i] - m) * r;
    v = v >= 0.f ? v : 0.1f * v;
    y[(size_t)c * S + i] = v;
    if (ycl) ycl[i * CP + c] = f2bf(v);
}

// ======================= cost volume + fused f1-channel copy =========
template<int C, int CP, int COPYC>
__global__ __launch_bounds__(256)
void costvolw_k(const float* __restrict__ f1, const float* __restrict__ f2,
                ushort* __restrict__ outcl, int D, int H, int W)
{
    const size_t S = (size_t)D * H * W;
    size_t p = (size_t)blockIdx.x * 4 + (threadIdx.x >> 6);
    if (p >= S) return;
    const int l = threadIdx.x & 63;
    int x = (int)(p % W); int y = (int)((p / W) % H); int z = (int)(p / ((size_t)W * H));
    float a[C];
#pragma unroll
    for (int c = 0; c < C; c++) a[c] = f1[(size_t)c * S + p];
    const float inv = 1.f / C;
    ushort* op = outcl + p * CP;
#pragma unroll
    for (int rep = 0; rep < 2; rep++) {
        int s = l + rep * 64;
        if (s < 125) {
            int v = s / 25 - 2, h = (s / 5) % 5 - 2, d = s % 5 - 2;
            int zz = z + v, yy = y + h, xx = x + d;
            float acc = 0.f;
            if ((unsigned)zz < (unsigned)D && (unsigned)yy < (unsigned)H &&
                (unsigned)xx < (unsigned)W) {
                size_t q = ((size_t)zz * H + yy) * (size_t)W + xx;
#pragma unroll
                for (int c = 0; c < C; c++) acc = fmaf(a[c], f2[(size_t)c * S + q], acc);
            }
            acc *= inv;
            op[s] = f2bf(acc >= 0.f ? acc : 0.1f * acc);
        }
    }
    if (COPYC && l < C)
        op[125 + l] = f2bf(f1[(size_t)l * S + p]);
}

// ======================= trilinear warp (clamped) =======================
__global__ __launch_bounds__(256)
void warp_k(const float* __restrict__ img, const float* __restrict__ flow,
            float* __restrict__ out, int C, int D, int H, int W)
{
    const size_t S = (size_t)D * H * W;
    size_t p = (size_t)blockIdx.x * 256 + threadIdx.x;
    if (p >= S) return;
    int x = (int)(p % W); int y = (int)((p / W) % H); int z = (int)(p / ((size_t)W * H));
    float cd = fminf(fmaxf((float)z + flow[p], 0.f), (float)(D - 1));
    float ch = fminf(fmaxf((float)y + flow[S + p], 0.f), (float)(H - 1));
    float cw = fminf(fmaxf((float)x + flow[2 * S + p], 0.f), (float)(W - 1));
    int d0 = (int)cd, h0 = (int)ch, w0 = (int)cw;
    float fd = cd - d0, fh = ch - h0, fw = cw - w0;
    int d1 = min(d0 + 1, D - 1), h1 = min(h0 + 1, H - 1), w1 = min(w0 + 1, W - 1);
    size_t i000 = ((size_t)d0 * H + h0) * W + w0, i001 = ((size_t)d0 * H + h0) * W + w1;
    size_t i010 = ((size_t)d0 * H + h1) * W + w0, i011 = ((size_t)d0 * H + h1) * W + w1;
    size_t i100 = ((size_t)d1 * H + h0) * W + w0, i101 = ((size_t)d1 * H + h0) * W + w1;
    size_t i110 = ((size_t)d1 * H + h1) * W + w0, i111 = ((size_t)d1 * H + h1) * W + w1;
    float w000 = (1 - fd) * (1 - fh) * (1 - fw), w001 = (1 - fd) * (1 - fh) * fw;
    float w010 = (1 - fd) * fh * (1 - fw),       w011 = (1 - fd) * fh * fw;
    float w100 = fd * (1 - fh) * (1 - fw),       w101 = fd * (1 - fh) * fw;
    float w110 = fd * fh * (1 - fw),             w111 = fd * fh * fw;
    for (int c = 0; c < C; c++) {
        const float* ic = img + (size_t)c * S;
        float v = w000 * ic[i000] + w001 * ic[i001] + w010 * ic[i010] + w011 * ic[i011]
                + w100 * ic[i100] + w101 * ic[i101] + w110 * ic[i110] + w111 * ic[i111];
        out[(size_t)c * S + p] = v;
    }
}

// ======================= host orchestration =======================
static void apply(hipStream_t st, float* x, int C, size_t S, const float* stats,
                  ushort* ycl, int CP)
{
    dim3 g((unsigned)DIVUP(S, 256), C);
    inorm_apply_k<<<g, 256, 0, st>>>(x, stats, x, S, 1.0f / (float)S, ycl, CP);
}

extern "C" void kernel_launch(void* const* d_in, const int* in_sizes, int n_in,
                              void* d_out, int out_size, void* d_ws, size_t ws_size,
                              hipStream_t st)
{
    (void)in_sizes; (void)n_in; (void)out_size; (void)ws_size;
    const float* atlas  = (const float*)d_in[0];
    const float* target = (const float*)d_in[1];
    const float *W_ct = (const float*)d_in[2],  *b_ct = (const float*)d_in[3];
    const float *W1a  = (const float*)d_in[4],  *b1a  = (const float*)d_in[5];
    const float *W1aa = (const float*)d_in[6],  *b1aa = (const float*)d_in[7];
    const float *W1b  = (const float*)d_in[8],  *b1b  = (const float*)d_in[9];
    const float *W2a  = (const float*)d_in[10], *b2a  = (const float*)d_in[11];
    const float *W2aa = (const float*)d_in[12], *b2aa = (const float*)d_in[13];
    const float *W2b  = (const float*)d_in[14], *b2b  = (const float*)d_in[15];
    const float *W20  = (const float*)d_in[16], *b20  = (const float*)d_in[17];
    const float *Wpf2 = (const float*)d_in[18], *bpf2 = (const float*)d_in[19];
    const float *Wd2  = (const float*)d_in[20], *bd2  = (const float*)d_in[21];
    const float *Wuf2 = (const float*)d_in[22], *buf2 = (const float*)d_in[23];
    const float *W10  = (const float*)d_in[24], *b10  = (const float*)d_in[25];
    const float *Wpf1 = (const float*)d_in[26], *bpf1 = (const float*)d_in[27];
    const float *Wd1  = (const float*)d_in[28], *bd1  = (const float*)d_in[29];
    const float *Wuf1 = (const float*)d_in[30], *buf1 = (const float*)d_in[31];
    const float *W00  = (const float*)d_in[32], *b00  = (const float*)d_in[33];
    const float *Wpf0 = (const float*)d_in[34], *bpf0 = (const float*)d_in[35];
    const float *Wd0  = (const float*)d_in[36], *bd0  = (const float*)d_in[37];

    const size_t S128 = 128u * 128 * 128, S64 = 64u * 64 * 64, S32 = 32u * 32 * 32, S16 = 16u * 16 * 16;

    char* base = (char*)d_ws;
    size_t off = 0;
    auto AF = [&](size_t n) { off = (off + 255) & ~(size_t)255; float* p = (float*)(base + off); off += n * 4; return p; };
    auto AH = [&](size_t n) { off = (off + 255) & ~(size_t)255; ushort* p = (ushort*)(base + off); off += n * 2; return p; };

    ushort* wp1a  = AH(13824);  ushort* wp1aa = AH(13824); ushort* wp1b = AH(13824);
    ushort* wp2a  = AH(27648);  ushort* wp2aa = AH(27648); ushort* wp2b = AH(27648);
    ushort* wp20  = AH(110592); ushort* wp10 = AH(138240); ushort* wp00 = AH(193536);
    ushort* wpf2  = AH(13824);  ushort* wpf1 = AH(13824);  ushort* wpf0 = AH(13824);
    ushort* wpd_uf1 = AH(131072);
    float* wt_uf2 = AF(6144);
    float* wt_d2  = AF(576);    float* wt_d1 = AF(576);    float* wt_d0 = AF(576);
    float* stats = AF(1024);
    float* im1  = AF(4 * S64);  float* im2 = AF(4 * S64);
    float* A1   = AF(16 * S32); ushort* A1cl = AH(S32 * 32);
    float* B1   = AF(16 * S32); ushort* B1cl = AH(S32 * 32);
    float* c11  = AF(16 * S32); ushort* c11cl = AH(S32 * 32);
    float* c21  = AF(16 * S32); ushort* c21cl = AH(S32 * 32);
    float* A2   = AF(32 * S16); ushort* A2cl = AH(S16 * 32);
    float* B2   = AF(32 * S16); ushort* B2cl = AH(S16 * 32);
    ushort* c12cl = AH(S16 * 32); ushort* c22cl = AH(S16 * 32);
    ushort* cv2cl = AH(S16 * 128);
    float* x20  = AF(32 * S16); ushort* x20cl = AH(S16 * 32);
    float* flow2 = AF(3 * S16); float* upflow2 = AF(3 * S32);
    float* warp1 = AF(16 * S32);
    ushort* x147cl = AH(S32 * 160);
    float* x10  = AF(32 * S32); ushort* x10cl = AH(S32 * 32);
    float* x10p1 = AF(32 * S32);
    float* flow1 = AF(3 * S32); float* upflow1 = AF(3 * S64);
    float* warp0 = AF(4 * S64);
    ushort* x196cl = AH(S64 * 224);
    float* x00  = AF(32 * S64); float* x00p1 = AF(32 * S64);
    float* flow0 = AF(3 * S64);

    ushort* im1cl = x196cl;
    ushort* im2cl = x196cl + 32 * S64;
    ushort* x00cl = x196cl;

    float* outF = (float*)d_out;
    float* c22o = outF + 3 * S128;
    float* c12o = c22o + 32 * S16;

    const int ST_IM2=0, ST_IM1=4, ST_A1a=8, ST_B1a=24, ST_C11=40, ST_A1b=56, ST_B1b=72,
              ST_C21=88, ST_A2a=104, ST_B2a=136, ST_C12=168, ST_A2b=200, ST_B2b=232,
              ST_C22=264, ST_X20=296, ST_X10=328, ST_X00=360;
    auto SP = [&](int o) { return stats + 2 * o; };
    hipMemsetAsync(stats, 0, 4096, st);

    WTab tab; int nb = 0, ti = 0;
    auto addw = [&](const float* s, void* d, int kind, int Cin, int COUT, int KC, int coutr) {
        int tot = (kind == 0) ? 27 * KC * (COUT >> 4) * 512
                 : (kind == 1) ? 8 * 8 * KC * 512 : Cin * COUT * 64;
        tab.t[ti] = WTask{s, d, kind, Cin, COUT, KC, coutr, nb};
        nb += DIVUP(tot, 256); ti++;
    };
    addw(W1a,  wp1a,  0,  4, 16, 1, 16);
    addw(W1aa, wp1aa, 0, 16, 16, 1, 16);
    addw(W1b,  wp1b,  0, 16, 16, 1, 16);
    addw(W2a,  wp2a,  0, 16, 32, 1, 32);
    addw(W2aa, wp2aa, 0, 32, 32, 1, 32);
    addw(W2b,  wp2b,  0, 32, 32, 1, 32);
    addw(W20,  wp20,  0, 125, 32, 4, 32);
    addw(W10,  wp10,  0, 147, 32, 5, 32);
    addw(W00,  wp00,  0, 196, 32, 7, 32);
    addw(Wpf2, wpf2,  0, 32, 16, 1, 3);
    addw(Wpf1, wpf1,  0, 32, 16, 1, 3);
    addw(Wpf0, wpf0,  0, 32, 16, 1, 3);
    addw(Wuf1, wpd_uf1, 1, 32, 64, 4, 64);
    addw(Wuf2, wt_uf2, 2, 32, 3, 0, 3);
    addw(Wd2,  wt_d2,  2, 3, 3, 0, 3);
    addw(Wd1,  wt_d1,  2, 3, 3, 0, 3);
    addw(Wd0,  wt_d0,  2, 3, 3, 0, 3);
    tab.n = ti;
    wprep_k<<<nb, 256, 0, st>>>(tab);

    // ---- stage A ----
    conv3x3_k<4, 2><<<dim3(8, 8, 16), 256, 0, st>>>(atlas, W_ct, b_ct, im2, SP(ST_IM2), 1, 128, 128, 128);
    apply(st, im2, 4, S64, SP(ST_IM2), im2cl, 32);
    conv3x3_k<4, 2><<<dim3(8, 8, 16), 256, 0, st>>>(target, W_ct, b_ct, im1, SP(ST_IM1), 1, 128, 128, 128);
    apply(st, im1, 4, S64, SP(ST_IM1), im1cl, 32);

    // ---- stage B (TH=8) ----
    mconv_k<32, 1, 2, 4, 16, 8><<<dim3(8, 8, 8), 256, 0, st>>>(im1cl, wp1a, b1a, A1, nullptr, SP(ST_A1a), 64, 64, 64, 8, 0);
    apply(st, A1, 16, S32, SP(ST_A1a), A1cl, 32);
    mconv_k<32, 1, 1, 2, 16, 8><<<dim3(4, 4, 16), 128, 0, st>>>(A1cl, wp1aa, b1aa, B1, nullptr, SP(ST_B1a), 32, 32, 32, 16, 0);
    apply(st, B1, 16, S32, SP(ST_B1a), B1cl, 32);
    mconv_k<32, 1, 1, 2, 16, 8><<<dim3(4, 4, 16), 128, 0, st>>>(B1cl, wp1b, b1b, c11, nullptr, SP(ST_C11), 32, 32, 32, 16, 0);
    apply(st, c11, 16, S32, SP(ST_C11), c11cl, 32);
    mconv_k<32, 1, 2, 4, 16, 8><<<dim3(8, 8, 8), 256, 0, st>>>(im2cl, wp1a, b1a, A1, nullptr, SP(ST_A1b), 64, 64, 64, 8, 0);
    apply(st, A1, 16, S32, SP(ST_A1b), A1cl, 32);
    mconv_k<32, 1, 1, 2, 16, 8><<<dim3(4, 4, 16), 128, 0, st>>>(A1cl, wp1aa, b1aa, B1, nullptr, SP(ST_B1b), 32, 32, 32, 16, 0);
    apply(st, B1, 16, S32, SP(ST_B1b), B1cl, 32);
    mconv_k<32, 1, 1, 2, 16, 8><<<dim3(4, 4, 16), 128, 0, st>>>(B1cl, wp1b, b1b, c21, nullptr, SP(ST_C21), 32, 32, 32, 16, 0);
    apply(st, c21, 16, S32, SP(ST_C21), c21cl, 32);

    // ---- stage C ----
    mconv_k<32, 2, 2, 4, 32, 8><<<dim3(4, 4, 4), 256, 0, st>>>(c11cl, wp2a, b2a, A2, nullptr, SP(ST_A2a), 32, 32, 32, 4, 0);
    apply(st, A2, 32, S16, SP(ST_A2a), A2cl, 32);
    mconv_k<32, 2, 1, 2, 32, 8><<<dim3(2, 2, 8), 128, 0, st>>>(A2cl, wp2aa, b2aa, B2, nullptr, SP(ST_B2a), 16, 16, 16, 8, 0);
    apply(st, B2, 32, S16, SP(ST_B2a), B2cl, 32);
    mconv_k<32, 2, 1, 2, 32, 8><<<dim3(2, 2, 8), 128, 0, st>>>(B2cl, wp2b, b2b, c12o, nullptr, SP(ST_C12), 16, 16, 16, 8, 0);
    apply(st, c12o, 32, S16, SP(ST_C12), c12cl, 32);
    mconv_k<32, 2, 2, 4, 32, 8><<<dim3(4, 4, 4), 256, 0, st>>>(c21cl, wp2a, b2a, A2, nullptr, SP(ST_A2b), 32, 32, 32, 4, 0);
    apply(st, A2, 32, S16, SP(ST_A2b), A2cl, 32);
    mconv_k<32, 2, 1, 2, 32, 8><<<dim3(2, 2, 8), 128, 0, st>>>(A2cl, wp2aa, b2aa, B2, nullptr, SP(ST_B2b), 16, 16, 16, 8, 0);
    apply(st, B2, 32, S16, SP(ST_B2b), B2cl, 32);
    mconv_k<32, 2, 1, 2, 32, 8><<<dim3(2, 2, 8), 128, 0, st>>>(B2cl, wp2b, b2b, c22o, nullptr, SP(ST_C22), 16, 16, 16, 8, 0);
    apply(st, c22o, 32, S16, SP(ST_C22), c22cl, 32);

    costvolw_k<32, 128, 0><<<DIVUP(S16, 4), 256, 0, st>>>(c12o, c22o, cv2cl, 16, 16, 16);
    mconv_k<128, 2, 1, 2, 32, 8><<<dim3(2, 2, 8), 128, 0, st>>>(cv2cl, wp20, b20, x20, nullptr, SP(ST_X20), 16, 16, 16, 8, 0);
    apply(st, x20, 32, S16, SP(ST_X20), x20cl, 32);
    mconv_k<32, 1, 1, 2, 3, 8><<<dim3(2, 2, 8), 128, 0, st>>>(x20cl, wpf2, bpf2, flow2, nullptr, nullptr, 16, 16, 16, 8, 0);
    dctn_k<3><<<DIVUP(8 * S16, 256), 256, 0, st>>>(flow2, wt_d2, bd2, upflow2, x147cl, 141, 160, 16);
    dctn_k<32><<<DIVUP(8 * S16, 256), 256, 0, st>>>(x20, wt_uf2, buf2, nullptr, x147cl, 144, 160, 16);

    // ---- stage D ----
    warp_k<<<DIVUP(S32, 256), 256, 0, st>>>(c21, upflow2, warp1, 16, 32, 32, 32);
    costvolw_k<16, 160, 1><<<DIVUP(S32, 4), 256, 0, st>>>(c11, warp1, x147cl, 32, 32, 32);
    mconv_k<160, 2, 1, 2, 32, 8><<<dim3(4, 4, 32), 128, 0, st>>>(x147cl, wp10, nullptr, x10, x10p1, nullptr, 32, 32, 32, 16, 3);
    sumred_k<<<dim3((unsigned)DIVUP(S32, 256), 32), 256, 0, st>>>(x10, x10p1, b10, x10, SP(ST_X10), S32);
    apply(st, x10, 32, S32, SP(ST_X10), x10cl, 32);
    mconv_k<32, 1, 1, 2, 3, 8><<<dim3(4, 4, 16), 128, 0, st>>>(x10cl, wpf1, bpf1, flow1, nullptr, nullptr, 32, 32, 32, 16, 0);
    dctn_k<3><<<DIVUP(8 * S32, 256), 256, 0, st>>>(flow1, wt_d1, bd1, upflow1, x196cl, 129, 224, 32);
    mdeconv_k<4><<<dim3(4, 4, 64), 256, 0, st>>>(x10cl, wpd_uf1, buf1, x196cl, 132, 224, 32);

    // ---- stage E ----
    warp_k<<<DIVUP(S64, 256), 256, 0, st>>>(im2, upflow1, warp0, 4, 64, 64, 64);
    costvolw_k<4, 224, 1><<<DIVUP(S64, 4), 256, 0, st>>>(im1, warp0, x196cl, 64, 64, 64);
    mconv_k<224, 2, 1, 4, 32, 8><<<dim3(8, 8, 32), 256, 0, st>>>(x196cl, wp00, nullptr, x00, x00p1, nullptr, 64, 64, 64, 16, 4);
    sumred_k<<<dim3((unsigned)DIVUP(S64, 256), 32), 256, 0, st>>>(x00, x00p1, b00, x00, SP(ST_X00), S64);
    apply(st, x00, 32, S64, SP(ST_X00), x00cl, 32);
    mconv_k<32, 1, 1, 4, 3, 8><<<dim3(8, 8, 16), 256, 0, st>>>(x00cl, wpf0, bpf0, flow0, nullptr, nullptr, 64, 64, 64, 16, 0);
    dctn_k<3><<<DIVUP(S128, 256), 256, 0, st>>>(flow0, wt_d0, bd0, outF, nullptr, 0, 0, 64);
}

// Round 8
// 1198.746 us; speedup vs baseline: 1.5671x; 1.5671x over previous
//
#include <hip/hip_runtime.h>
#include <cstddef>
#include <cstdint>

#define DIVUP(a,b) (((a)+(b)-1)/(b))

typedef __attribute__((ext_vector_type(8))) short short8;
typedef __attribute__((ext_vector_type(4))) float f32x4;

__device__ __forceinline__ ushort f2bf(float f) {
    union { float f; uint32_t u; } v; v.f = f;
    uint32_t r = v.u + 0x7fffu + ((v.u >> 16) & 1u);
    return (ushort)(r >> 16);
}

// ======================= fp32 direct conv (Cin=1 stride-2 encoder) + fused stats ====
template<int COUT, int STRIDE>
__global__ __launch_bounds__(256)
void conv3x3_k(const float* __restrict__ in, const float* __restrict__ wgt,
               const float* __restrict__ bias, float* __restrict__ out,
               float* __restrict__ stats, int Cin, int D, int H, int W)
{
    constexpr int TD = 4, TH = 8, TW = 8;
    constexpr int ID = (STRIDE == 1) ? TD + 2 : 2 * TD + 1;
    constexpr int IH = (STRIDE == 1) ? TH + 2 : 2 * TH + 1;
    constexpr int IW = (STRIDE == 1) ? TW + 2 : 2 * TW + 1;
    __shared__ float tile[ID * IH * IW];
    const int Do = D / STRIDE, Ho = H / STRIDE, Wo = W / STRIDE;
    const int tid = threadIdx.x;
    const int tw = tid & 7, th = (tid >> 3) & 7, td = tid >> 6;
    const int ow0 = blockIdx.x * TW, oh0 = blockIdx.y * TH, od0 = blockIdx.z * TD;
    const int iw0 = ow0 * STRIDE - 1, ih0 = oh0 * STRIDE - 1, id0 = od0 * STRIDE - 1;
    const size_t HWs = (size_t)H * W;

    float acc[COUT];
#pragma unroll
    for (int i = 0; i < COUT; i++) acc[i] = 0.f;

    for (int c = 0; c < Cin; ++c) {
        const float* inc = in + (size_t)c * D * HWs;
        for (int i = tid; i < ID * IH * IW; i += 256) {
            int lw = i % IW, lh = (i / IW) % IH, ld = i / (IW * IH);
            int gw = iw0 + lw, gh = ih0 + lh, gd = id0 + ld;
            float v = 0.f;
            if ((unsigned)gw < (unsigned)W && (unsigned)gh < (unsigned)H &&
                (unsigned)gd < (unsigned)D)
                v = inc[(size_t)gd * HWs + (size_t)gh * W + gw];
            tile[i] = v;
        }
        __syncthreads();
        float r[27];
        const int bd = td * STRIDE, bh = th * STRIDE, bw = tw * STRIDE;
#pragma unroll
        for (int kd = 0; kd < 3; kd++)
#pragma unroll
            for (int kh = 0; kh < 3; kh++)
#pragma unroll
                for (int kw = 0; kw < 3; kw++)
                    r[kd * 9 + kh * 3 + kw] =
                        tile[(bd + kd) * (IH * IW) + (bh + kh) * IW + (bw + kw)];
#pragma unroll
        for (int oc = 0; oc < COUT; ++oc) {
            const float* wp = wgt + ((size_t)oc * Cin + c) * 27;
            float s = 0.f;
#pragma unroll
            for (int t = 0; t < 27; t++) s = fmaf(wp[t], r[t], s);
            acc[oc] += s;
        }
        __syncthreads();
    }
    const size_t So = (size_t)Do * Ho * Wo;
    const size_t sp = (size_t)(od0 + td) * Ho * Wo + (size_t)(oh0 + th) * Wo + (ow0 + tw);
#pragma unroll
    for (int oc = 0; oc < COUT; ++oc)
        out[(size_t)oc * So + sp] = acc[oc] + bias[oc];

    if (stats) {
        __syncthreads();
        float* sm = tile;
        const int wv = tid >> 6, l = tid & 63;
#pragma unroll
        for (int oc = 0; oc < COUT; ++oc) {
            float sv = acc[oc] + bias[oc];
            float sq = sv * sv;
#pragma unroll
            for (int o = 32; o > 0; o >>= 1) {
                sv += __shfl_down(sv, o, 64);
                sq += __shfl_down(sq, o, 64);
            }
            if (l == 0) { sm[(wv * COUT + oc) * 2] = sv; sm[(wv * COUT + oc) * 2 + 1] = sq; }
        }
        __syncthreads();
        if (tid < COUT) {
            float s = 0.f, s2 = 0.f;
#pragma unroll
            for (int w = 0; w < 4; ++w) {
                s += sm[(w * COUT + tid) * 2];
                s2 += sm[(w * COUT + tid) * 2 + 1];
            }
            atomicAdd(&stats[2 * tid], s);
            atomicAdd(&stats[2 * tid + 1], s2);
        }
    }
}

// ======================= MFMA implicit-GEMM conv (TH=8, fused stats) ============
// Register-prefetch pipeline; 9-row A-frag reuse; stats via staggered atomics
// (safe only because this kernel is long — see R7 post-mortem).
template<int CP, int NF, int STRIDE, int MW, int COUTR>
__global__ __launch_bounds__(MW * 64)
void mconv_k(const ushort* __restrict__ xcl, const ushort* __restrict__ wp,
             const float* __restrict__ bias, float* __restrict__ outcf,
             float* __restrict__ stats, int D, int H, int W)
{
    constexpr int KC = CP / 32;
    constexpr int MF = (STRIDE == 1) ? 4 : 1;
    constexpr int TD = MW;
    constexpr int TWl = (STRIDE == 1) ? 8 : 4;
    constexpr int HD = (STRIDE == 1) ? TD + 2 : 2 * TD + 1;
    constexpr int HH = (STRIDE == 1) ? 10 : 9;
    constexpr int HWd = (STRIDE == 1) ? 10 : 9;
    constexpr int HALO = HD * HH * HWd;
    constexpr int NTH = MW * 64;
    constexpr int NIT = (HALO * 4 + NTH - 1) / NTH;
    __shared__ __align__(16) ushort lds[HALO * 40];

    const int tid = threadIdx.x;
    const int wv = tid >> 6, l = tid & 63;
    const int od0 = blockIdx.z * TD, oh0 = blockIdx.y * ((STRIDE == 1) ? 8 : 4),
              ow0 = blockIdx.x * TWl;
    const int id0 = od0 * STRIDE - 1, ih0 = oh0 * STRIDE - 1, iw0 = ow0 * STRIDE - 1;

    f32x4 acc[MF][NF];
#pragma unroll
    for (int mf = 0; mf < MF; mf++)
#pragma unroll
        for (int nf = 0; nf < NF; nf++) acc[mf][nf] = f32x4{0.f, 0.f, 0.f, 0.f};

    uint4 v[NIT];
    auto stage = [&](int kc) {
#pragma unroll
        for (int it = 0; it < NIT; ++it) {
            int idx = it * NTH + tid;
            uint4 t = {0u, 0u, 0u, 0u};
            if (idx < HALO * 4) {
                int pt = idx >> 2, part = idx & 3;
                int lw = pt % HWd, lh = (pt / HWd) % HH, ld = pt / (HWd * HH);
                int gx = iw0 + lw, gy = ih0 + lh, gz = id0 + ld;
                if ((unsigned)gx < (unsigned)W && (unsigned)gy < (unsigned)H &&
                    (unsigned)gz < (unsigned)D)
                    t = *reinterpret_cast<const uint4*>(
                        xcl + ((size_t)((gz * H + gy) * W + gx)) * CP + kc * 32 + part * 8);
            }
            v[it] = t;
        }
    };

    stage(0);
    for (int kc = 0; kc < KC; ++kc) {
        if (kc) __syncthreads();
#pragma unroll
        for (int it = 0; it < NIT; ++it) {
            int idx = it * NTH + tid;
            if (idx < HALO * 4)
                *reinterpret_cast<uint4*>(&lds[(idx >> 2) * 40 + (idx & 3) * 8]) = v[it];
        }
        __syncthreads();
        if (kc + 1 < KC) stage(kc + 1);
        if constexpr (STRIDE == 1) {
#pragma unroll
            for (int kd = 0; kd < 3; ++kd) {
#pragma unroll
                for (int kw = 0; kw < 3; ++kw) {
                    short8 af[9];
#pragma unroll
                    for (int r = 0; r < 9; ++r)
                        af[r] = *reinterpret_cast<const short8*>(
                            &lds[((wv + kd) * (HH * HWd) +
                                  (r + ((l >> 3) & 1)) * HWd + (l & 7) + kw) * 40 +
                                 ((l >> 4) << 3)]);
#pragma unroll
                    for (int kh = 0; kh < 3; ++kh) {
                        const int t = kd * 9 + kh * 3 + kw;
                        short8 bf[NF];
#pragma unroll
                        for (int nf = 0; nf < NF; ++nf)
                            bf[nf] = *reinterpret_cast<const short8*>(
                                wp + (((size_t)(t * KC + kc) * NF + nf) << 9) + (l << 3));
#pragma unroll
                        for (int mf = 0; mf < MF; ++mf)
#pragma unroll
                            for (int nf = 0; nf < NF; ++nf)
                                acc[mf][nf] = __builtin_amdgcn_mfma_f32_16x16x32_bf16(
                                    af[2 * mf + kh], bf[nf], acc[mf][nf], 0, 0, 0);
                    }
                }
            }
        } else {
#pragma unroll
            for (int t = 0; t < 27; ++t) {
                const int kd = t / 9, kh = (t / 3) % 3, kw = t % 3;
                short8 bf[NF];
#pragma unroll
                for (int nf = 0; nf < NF; ++nf)
                    bf[nf] = *reinterpret_cast<const short8*>(
                        wp + (((size_t)(t * KC + kc) * NF + nf) << 9) + (l << 3));
                int bw = l & 3, bh = (l >> 2) & 3;
                int p_loc = (2 * wv + kd) * (HH * HWd) + (2 * bh + kh) * HWd + (2 * bw + kw);
                short8 afs = *reinterpret_cast<const short8*>(&lds[p_loc * 40 + ((l >> 4) << 3)]);
#pragma unroll
                for (int nf = 0; nf < NF; ++nf)
                    acc[0][nf] = __builtin_amdgcn_mfma_f32_16x16x32_bf16(
                        afs, bf[nf], acc[0][nf], 0, 0, 0);
            }
        }
    }
    const int Do = D / STRIDE, Ho = H / STRIDE, Wo = W / STRIDE;
    const size_t So = (size_t)Do * Ho * Wo;
    float ps[NF], ps2[NF];
#pragma unroll
    for (int nf = 0; nf < NF; ++nf) { ps[nf] = 0.f; ps2[nf] = 0.f; }
#pragma unroll
    for (int nf = 0; nf < NF; ++nf) {
        int oc = nf * 16 + (l & 15);
        float bv = (oc < COUTR) ? bias[oc] : 0.f;
#pragma unroll
        for (int mf = 0; mf < MF; ++mf) {
#pragma unroll
            for (int r = 0; r < 4; ++r) {
                int q = ((l >> 4) << 2) + r;
                int bw, bh;
                if (STRIDE == 1) { bw = q & 7; bh = 2 * mf + (q >> 3); }
                else             { bw = q & 3; bh = (q >> 2) & 3; }
                int p = ((od0 + wv) * Ho + (oh0 + bh)) * Wo + (ow0 + bw);
                float val = acc[mf][nf][r] + bv;
                if (oc < COUTR) {
                    outcf[(size_t)oc * So + p] = val;
                    ps[nf] += val; ps2[nf] = fmaf(val, val, ps2[nf]);
                }
            }
        }
    }
    if (stats) {
        __syncthreads();
        float* sm = (float*)lds;
#pragma unroll
        for (int nf = 0; nf < NF; ++nf) {
            float s = ps[nf], s2 = ps2[nf];
            s += __shfl_down(s, 32, 64);  s2 += __shfl_down(s2, 32, 64);
            s += __shfl_down(s, 16, 64);  s2 += __shfl_down(s2, 16, 64);
            if (l < 16) {
                sm[((wv * NF + nf) * 16 + l) * 2] = s;
                sm[((wv * NF + nf) * 16 + l) * 2 + 1] = s2;
            }
        }
        __syncthreads();
        if (tid < NF * 16) {
            int nf = tid >> 4, c = tid & 15, oc = nf * 16 + c;
            if (oc < COUTR) {
                float s = 0.f, s2 = 0.f;
#pragma unroll
                for (int w = 0; w < MW; ++w) {
                    s += sm[((w * NF + nf) * 16 + c) * 2];
                    s2 += sm[((w * NF + nf) * 16 + c) * 2 + 1];
                }
                atomicAdd(&stats[2 * oc], s);
                atomicAdd(&stats[2 * oc + 1], s2);
            }
        }
    }
}

// ======================= consolidated weight prep ============================
struct WTask { const float* src; void* dst; int kind, Cin, COUT, KC, coutr, base; };
struct WTab { WTask t[17]; int n; };

__global__ __launch_bounds__(256)
void wprep_k(WTab tab)
{
    int b = blockIdx.x, ti = 0;
    for (int i = 0; i < tab.n; ++i) if (b >= tab.t[i].base) ti = i;
    const WTask tk = tab.t[ti];
    int idx = (b - tk.base) * 256 + threadIdx.x;
    if (tk.kind == 0) {
        int NF = tk.COUT >> 4;
        int tot = 27 * tk.KC * NF * 512;
        if (idx >= tot) return;
        int j = idx & 7, l = (idx >> 3) & 63;
        int g = idx >> 9;
        int nf = g % NF; g /= NF;
        int kc = g % tk.KC; int t = g / tk.KC;
        int oc = nf * 16 + (l & 15);
        int c = kc * 32 + ((l >> 4) << 3) + j;
        float v = (c < tk.Cin && oc < tk.coutr)
                      ? tk.src[((size_t)oc * tk.Cin + c) * 27 + t] : 0.f;
        ((ushort*)tk.dst)[idx] = f2bf(v);
    } else if (tk.kind == 1) {
        int NF = tk.KC;
        int tot = 8 * 8 * NF * 512;
        if (idx >= tot) return;
        int j = idx & 7, l = (idx >> 3) & 63;
        int g = idx >> 9;
        int nf = g % NF; g /= NF;
        int t = g % 8; int pp = g / 8;
        int oc = nf * 16 + (l & 15);
        int c = ((l >> 4) << 3) + j;
        int kd_ = (t >> 2) & 1, kh_ = (t >> 1) & 1, kw_ = t & 1;
        int pd = (pp >> 2) & 1, ph = (pp >> 1) & 1, pw = pp & 1;
        int kd = 3 - pd - 2 * kd_, kh = 3 - ph - 2 * kh_, kw = 3 - pw - 2 * kw_;
        float v = (oc < tk.COUT)
                      ? tk.src[(size_t)(c * tk.COUT + oc) * 64 + kd * 16 + kh * 4 + kw] : 0.f;
        ((ushort*)tk.dst)[idx] = f2bf(v);
    } else {
        int tot = tk.Cin * tk.COUT * 64;
        if (idx >= tot) return;
        int k = idx & 63; int oc = (idx >> 6) % tk.COUT; int c = (idx >> 6) / tk.COUT;
        ((float*)tk.dst)[((size_t)c * 64 + k) * tk.COUT + oc] = tk.src[idx];
    }
}

// ======================= MFMA deconv (uf1) =======================
template<int NF>
__global__ __launch_bounds__(256)
void mdeconv_k(const ushort* __restrict__ xcl, const ushort* __restrict__ wpd,
               const float* __restrict__ bias, ushort* __restrict__ outcl,
               int c0, int CPo, int Si)
{
    constexpr int HD = 5, HH = 9, HWd = 9, HALO = HD * HH * HWd;
    __shared__ __align__(16) ushort lds[HALO * 40];
    const int tid = threadIdx.x, wv = tid >> 6, l = tid & 63;
    const int pp = blockIdx.z & 7, tz = blockIdx.z >> 3;
    const int pd = (pp >> 2) & 1, ph = (pp >> 1) & 1, pw = pp & 1;
    const int oz0 = tz * 4, oy0 = blockIdx.y * 8, ox0 = blockIdx.x * 8;
    const int iz0 = oz0 + pd - 1, iy0 = oy0 + ph - 1, ix0 = ox0 + pw - 1;

    for (int idx = tid; idx < HALO * 4; idx += 256) {
        int pt = idx >> 2, part = idx & 3;
        int lw = pt % HWd, lh = (pt / HWd) % HH, ld = pt / (HWd * HH);
        int gx = ix0 + lw, gy = iy0 + lh, gz = iz0 + ld;
        uint4 t = {0u, 0u, 0u, 0u};
        if ((unsigned)gx < (unsigned)Si && (unsigned)gy < (unsigned)Si &&
            (unsigned)gz < (unsigned)Si)
            t = *reinterpret_cast<const uint4*>(
                xcl + ((size_t)((gz * Si + gy) * Si + gx)) * 32 + part * 8);
        *reinterpret_cast<uint4*>(&lds[pt * 40 + part * 8]) = t;
    }
    __syncthreads();

    f32x4 acc[4][NF];
#pragma unroll
    for (int mf = 0; mf < 4; mf++)
#pragma unroll
        for (int nf = 0; nf < NF; nf++) acc[mf][nf] = f32x4{0.f, 0.f, 0.f, 0.f};

#pragma unroll
    for (int kd = 0; kd < 2; ++kd) {
#pragma unroll
        for (int kw = 0; kw < 2; ++kw) {
            short8 af[8];
#pragma unroll
            for (int r = 0; r < 8; ++r)
                af[r] = *reinterpret_cast<const short8*>(
                    &lds[((wv + kd) * (HH * HWd) + (r + ((l >> 3) & 1)) * HWd +
                          (l & 7) + kw) * 40 + ((l >> 4) << 3)]);
#pragma unroll
            for (int kh = 0; kh < 2; ++kh) {
                const int t = kd * 4 + kh * 2 + kw;
                short8 bf[NF];
#pragma unroll
                for (int nf = 0; nf < NF; ++nf)
                    bf[nf] = *reinterpret_cast<const short8*>(
                        wpd + (((size_t)(pp * 8 + t) * NF + nf) << 9) + (l << 3));
#pragma unroll
                for (int mf = 0; mf < 4; ++mf)
#pragma unroll
                    for (int nf = 0; nf < NF; ++nf)
                        acc[mf][nf] = __builtin_amdgcn_mfma_f32_16x16x32_bf16(
                            af[2 * mf + kh], bf[nf], acc[mf][nf], 0, 0, 0);
            }
        }
    }
    const int Do = 2 * Si;
#pragma unroll
    for (int nf = 0; nf < NF; ++nf) {
        int oc = nf * 16 + (l & 15);
        float bv = bias[oc];
#pragma unroll
        for (int mf = 0; mf < 4; ++mf) {
#pragma unroll
            for (int r = 0; r < 4; ++r) {
                int q = ((l >> 4) << 2) + r;
                int bw = q & 7, bh = 2 * mf + (q >> 3);
                int oD = 2 * (oz0 + wv) + pd, oH = 2 * (oy0 + bh) + ph, oW = 2 * (ox0 + bw) + pw;
                outcl[(size_t)((oD * Do + oH) * Do + oW) * CPo + c0 + oc] =
                    f2bf(acc[mf][nf][r] + bv);
            }
        }
    }
}

// ======================= output-centric small deconv (COUT=3) ====
template<int CIN>
__global__ __launch_bounds__(256)
void dctn_k(const float* __restrict__ in, const float* __restrict__ wt,
            const float* __restrict__ bias, float* __restrict__ outcf,
            ushort* __restrict__ outcl, int c0, int CPo, int Si)
{
    const int Do = 2 * Si;
    const size_t So = (size_t)Do * Do * Do, ni = (size_t)Si * Si * Si;
    size_t p = (size_t)blockIdx.x * 256 + threadIdx.x;
    if (p >= So) return;
    int oxW = (int)(p % Do), oyH = (int)((p / Do) % Do), ozD = (int)(p / ((size_t)Do * Do));
    int pw = oxW & 1, ph = oyH & 1, pd = ozD & 1;
    int xb = oxW >> 1, yb = oyH >> 1, zb = ozD >> 1;
    float acc[3] = {0.f, 0.f, 0.f};
    for (int c = 0; c < CIN; ++c) {
        const float* inc = in + (size_t)c * ni;
        const float* wc = wt + (size_t)c * 64 * 3;
#pragma unroll
        for (int jd = 0; jd < 2; jd++) {
            int iz = zb + pd - jd; if ((unsigned)iz >= (unsigned)Si) continue;
            int kd = 1 - pd + 2 * jd;
#pragma unroll
            for (int jh = 0; jh < 2; jh++) {
                int iy = yb + ph - jh; if ((unsigned)iy >= (unsigned)Si) continue;
                int kh = 1 - ph + 2 * jh;
#pragma unroll
                for (int jw = 0; jw < 2; jw++) {
                    int ix = xb + pw - jw; if ((unsigned)ix >= (unsigned)Si) continue;
                    int kw = 1 - pw + 2 * jw;
                    float v = inc[((size_t)iz * Si + iy) * Si + ix];
                    const float* wr = wc + (size_t)((kd * 4 + kh) * 4 + kw) * 3;
                    acc[0] = fmaf(wr[0], v, acc[0]);
                    acc[1] = fmaf(wr[1], v, acc[1]);
                    acc[2] = fmaf(wr[2], v, acc[2]);
                }
            }
        }
    }
#pragma unroll
    for (int oc = 0; oc < 3; ++oc) {
        float o = acc[oc] + bias[oc];
        if (outcf) outcf[(size_t)oc * So + p] = o;
        if (outcl) outcl[p * CPo + c0 + oc] = f2bf(o);
    }
}

// ======================= instance norm apply =======================
__global__ __launch_bounds__(256)
void inorm_apply_k(const float* __restrict__ x, const float* __restrict__ stats,
                   float* __restrict__ y, size_t S, float invS,
                   ushort* __restrict__ ycl, int CP)
{
    int c = blockIdx.y;
    float sum = stats[2 * c], ss = stats[2 * c + 1];
    float m = sum * invS;
    float r = rsqrtf(fmaxf(ss * invS - m * m, 0.f) + 1e-5f);
    size_t i = (size_t)blockIdx.x * 256 + threadIdx.x;
    if (i >= S) return;
    float v = (x[(size_t)c * S + i] - m) * r;
    v = v >= 0.f ? v : 0.1f * v;
    y[(size_t)c * S + i] = v;
    if (ycl) ycl[i * CP + c] = f2bf(v);
}

// ======================= cost volume + fused f1-channel copy =========
template<int C, int CP, int COPYC>
__global__ __launch_bounds__(256)
void costvolw_k(const float* __restrict__ f1, const float* __restrict__ f2,
                ushort* __restrict__ outcl, int D, int H, int W)
{
    const size_t S = (size_t)D * H * W;
    size_t p = (size_t)blockIdx.x * 4 + (threadIdx.x >> 6);
    if (p >= S) return;
    const int l = threadIdx.x & 63;
    int x = (int)(p % W); int y = (int)((p / W) % H); int z = (int)(p / ((size_t)W * H));
    float a[C];
#pragma unroll
    for (int c = 0; c < C; c++) a[c] = f1[(size_t)c * S + p];
    const float inv = 1.f / C;
    ushort* op = outcl + p * CP;
#pragma unroll
    for (int rep = 0; rep < 2; rep++) {
        int s = l + rep * 64;
        if (s < 125) {
            int v = s / 25 - 2, h = (s / 5) % 5 - 2, d = s % 5 - 2;
            int zz = z + v, yy = y + h, xx = x + d;
            float acc = 0.f;
            if ((unsigned)zz < (unsigned)D && (unsigned)yy < (unsigned)H &&
                (unsigned)xx < (unsigned)W) {
                size_t q = ((size_t)zz * H + yy) * (size_t)W + xx;
#pragma unroll
                for (int c = 0; c < C; c++) acc = fmaf(a[c], f2[(size_t)c * S + q], acc);
            }
            acc *= inv;
            op[s] = f2bf(acc >= 0.f ? acc : 0.1f * acc);
        }
    }
    if (COPYC && l < C)
        op[125 + l] = f2bf(f1[(size_t)l * S + p]);
}

// ======================= trilinear warp (clamped) =======================
__global__ __launch_bounds__(256)
void warp_k(const float* __restrict__ img, const float* __restrict__ flow,
            float* __restrict__ out, int C, int D, int H, int W)
{
    const size_t S = (size_t)D * H * W;
    size_t p = (size_t)blockIdx.x * 256 + threadIdx.x;
    if (p >= S) return;
    int x = (int)(p % W); int y = (int)((p / W) % H); int z = (int)(p / ((size_t)W * H));
    float cd = fminf(fmaxf((float)z + flow[p], 0.f), (float)(D - 1));
    float ch = fminf(fmaxf((float)y + flow[S + p], 0.f), (float)(H - 1));
    float cw = fminf(fmaxf((float)x + flow[2 * S + p], 0.f), (float)(W - 1));
    int d0 = (int)cd, h0 = (int)ch, w0 = (int)cw;
    float fd = cd - d0, fh = ch - h0, fw = cw - w0;
    int d1 = min(d0 + 1, D - 1), h1 = min(h0 + 1, H - 1), w1 = min(w0 + 1, W - 1);
    size_t i000 = ((size_t)d0 * H + h0) * W + w0, i001 = ((size_t)d0 * H + h0) * W + w1;
    size_t i010 = ((size_t)d0 * H + h1) * W + w0, i011 = ((size_t)d0 * H + h1) * W + w1;
    size_t i100 = ((size_t)d1 * H + h0) * W + w0, i101 = ((size_t)d1 * H + h0) * W + w1;
    size_t i110 = ((size_t)d1 * H + h1) * W + w0, i111 = ((size_t)d1 * H + h1) * W + w1;
    float w000 = (1 - fd) * (1 - fh) * (1 - fw), w001 = (1 - fd) * (1 - fh) * fw;
    float w010 = (1 - fd) * fh * (1 - fw),       w011 = (1 - fd) * fh * fw;
    float w100 = fd * (1 - fh) * (1 - fw),       w101 = fd * (1 - fh) * fw;
    float w110 = fd * fh * (1 - fw),             w111 = fd * fh * fw;
    for (int c = 0; c < C; c++) {
        const float* ic = img + (size_t)c * S;
        float v = w000 * ic[i000] + w001 * ic[i001] + w010 * ic[i010] + w011 * ic[i011]
                + w100 * ic[i100] + w101 * ic[i101] + w110 * ic[i110] + w111 * ic[i111];
        out[(size_t)c * S + p] = v;
    }
}

// ======================= host orchestration =======================
static void apply(hipStream_t st, float* x, int C, size_t S, const float* stats,
                  ushort* ycl, int CP)
{
    dim3 g((unsigned)DIVUP(S, 256), C);
    inorm_apply_k<<<g, 256, 0, st>>>(x, stats, x, S, 1.0f / (float)S, ycl, CP);
}

extern "C" void kernel_launch(void* const* d_in, const int* in_sizes, int n_in,
                              void* d_out, int out_size, void* d_ws, size_t ws_size,
                              hipStream_t st)
{
    (void)in_sizes; (void)n_in; (void)out_size; (void)ws_size;
    const float* atlas  = (const float*)d_in[0];
    const float* target = (const float*)d_in[1];
    const float *W_ct = (const float*)d_in[2],  *b_ct = (const float*)d_in[3];
    const float *W1a  = (const float*)d_in[4],  *b1a  = (const float*)d_in[5];
    const float *W1aa = (const float*)d_in[6],  *b1aa = (const float*)d_in[7];
    const float *W1b  = (const float*)d_in[8],  *b1b  = (const float*)d_in[9];
    const float *W2a  = (const float*)d_in[10], *b2a  = (const float*)d_in[11];
    const float *W2aa = (const float*)d_in[12], *b2aa = (const float*)d_in[13];
    const float *W2b  = (const float*)d_in[14], *b2b  = (const float*)d_in[15];
    const float *W20  = (const float*)d_in[16], *b20  = (const float*)d_in[17];
    const float *Wpf2 = (const float*)d_in[18], *bpf2 = (const float*)d_in[19];
    const float *Wd2  = (const float*)d_in[20], *bd2  = (const float*)d_in[21];
    const float *Wuf2 = (const float*)d_in[22], *buf2 = (const float*)d_in[23];
    const float *W10  = (const float*)d_in[24], *b10  = (const float*)d_in[25];
    const float *Wpf1 = (const float*)d_in[26], *bpf1 = (const float*)d_in[27];
    const float *Wd1  = (const float*)d_in[28], *bd1  = (const float*)d_in[29];
    const float *Wuf1 = (const float*)d_in[30], *buf1 = (const float*)d_in[31];
    const float *W00  = (const float*)d_in[32], *b00  = (const float*)d_in[33];
    const float *Wpf0 = (const float*)d_in[34], *bpf0 = (const float*)d_in[35];
    const float *Wd0  = (const float*)d_in[36], *bd0  = (const float*)d_in[37];

    const size_t S128 = 128u * 128 * 128, S64 = 64u * 64 * 64, S32 = 32u * 32 * 32, S16 = 16u * 16 * 16;

    char* base = (char*)d_ws;
    size_t off = 0;
    auto AF = [&](size_t n) { off = (off + 255) & ~(size_t)255; float* p = (float*)(base + off); off += n * 4; return p; };
    auto AH = [&](size_t n) { off = (off + 255) & ~(size_t)255; ushort* p = (ushort*)(base + off); off += n * 2; return p; };

    ushort* wp1a  = AH(13824);  ushort* wp1aa = AH(13824); ushort* wp1b = AH(13824);
    ushort* wp2a  = AH(27648);  ushort* wp2aa = AH(27648); ushort* wp2b = AH(27648);
    ushort* wp20  = AH(110592); ushort* wp10 = AH(138240); ushort* wp00 = AH(193536);
    ushort* wpf2  = AH(13824);  ushort* wpf1 = AH(13824);  ushort* wpf0 = AH(13824);
    ushort* wpd_uf1 = AH(131072);
    float* wt_uf2 = AF(6144);
    float* wt_d2  = AF(576);    float* wt_d1 = AF(576);    float* wt_d0 = AF(576);
    float* stats = AF(1024);
    float* im1  = AF(4 * S64);  float* im2 = AF(4 * S64);
    float* A1   = AF(16 * S32); ushort* A1cl = AH(S32 * 32);
    float* B1   = AF(16 * S32); ushort* B1cl = AH(S32 * 32);
    float* c11  = AF(16 * S32); ushort* c11cl = AH(S32 * 32);
    float* c21  = AF(16 * S32); ushort* c21cl = AH(S32 * 32);
    float* A2   = AF(32 * S16); ushort* A2cl = AH(S16 * 32);
    float* B2   = AF(32 * S16); ushort* B2cl = AH(S16 * 32);
    ushort* c12cl = AH(S16 * 32); ushort* c22cl = AH(S16 * 32);
    ushort* cv2cl = AH(S16 * 128);
    float* x20  = AF(32 * S16); ushort* x20cl = AH(S16 * 32);
    float* flow2 = AF(3 * S16); float* upflow2 = AF(3 * S32);
    float* warp1 = AF(16 * S32);
    ushort* x147cl = AH(S32 * 160);
    float* x10  = AF(32 * S32); ushort* x10cl = AH(S32 * 32);
    float* flow1 = AF(3 * S32); float* upflow1 = AF(3 * S64);
    float* warp0 = AF(4 * S64);
    ushort* x196cl = AH(S64 * 224);
    float* x00  = AF(32 * S64); float* flow0 = AF(3 * S64);

    ushort* im1cl = x196cl;
    ushort* im2cl = x196cl + 32 * S64;
    ushort* x00cl = x196cl;

    float* outF = (float*)d_out;
    float* c22o = outF + 3 * S128;
    float* c12o = c22o + 32 * S16;

    const int ST_IM2=0, ST_IM1=4, ST_A1a=8, ST_B1a=24, ST_C11=40, ST_A1b=56, ST_B1b=72,
              ST_C21=88, ST_A2a=104, ST_B2a=136, ST_C12=168, ST_A2b=200, ST_B2b=232,
              ST_C22=264, ST_X20=296, ST_X10=328, ST_X00=360;
    auto SP = [&](int o) { return stats + 2 * o; };
    hipMemsetAsync(stats, 0, 4096, st);

    WTab tab; int nb = 0, ti = 0;
    auto addw = [&](const float* s, void* d, int kind, int Cin, int COUT, int KC, int coutr) {
        int tot = (kind == 0) ? 27 * KC * (COUT >> 4) * 512
                 : (kind == 1) ? 8 * 8 * KC * 512 : Cin * COUT * 64;
        tab.t[ti] = WTask{s, d, kind, Cin, COUT, KC, coutr, nb};
        nb += DIVUP(tot, 256); ti++;
    };
    addw(W1a,  wp1a,  0,  4, 16, 1, 16);
    addw(W1aa, wp1aa, 0, 16, 16, 1, 16);
    addw(W1b,  wp1b,  0, 16, 16, 1, 16);
    addw(W2a,  wp2a,  0, 16, 32, 1, 32);
    addw(W2aa, wp2aa, 0, 32, 32, 1, 32);
    addw(W2b,  wp2b,  0, 32, 32, 1, 32);
    addw(W20,  wp20,  0, 125, 32, 4, 32);
    addw(W10,  wp10,  0, 147, 32, 5, 32);
    addw(W00,  wp00,  0, 196, 32, 7, 32);
    addw(Wpf2, wpf2,  0, 32, 16, 1, 3);
    addw(Wpf1, wpf1,  0, 32, 16, 1, 3);
    addw(Wpf0, wpf0,  0, 32, 16, 1, 3);
    addw(Wuf1, wpd_uf1, 1, 32, 64, 4, 64);
    addw(Wuf2, wt_uf2, 2, 32, 3, 0, 3);
    addw(Wd2,  wt_d2,  2, 3, 3, 0, 3);
    addw(Wd1,  wt_d1,  2, 3, 3, 0, 3);
    addw(Wd0,  wt_d0,  2, 3, 3, 0, 3);
    tab.n = ti;
    wprep_k<<<nb, 256, 0, st>>>(tab);

    // ---- stage A ----
    conv3x3_k<4, 2><<<dim3(8, 8, 16), 256, 0, st>>>(atlas, W_ct, b_ct, im2, SP(ST_IM2), 1, 128, 128, 128);
    apply(st, im2, 4, S64, SP(ST_IM2), im2cl, 32);
    conv3x3_k<4, 2><<<dim3(8, 8, 16), 256, 0, st>>>(target, W_ct, b_ct, im1, SP(ST_IM1), 1, 128, 128, 128);
    apply(st, im1, 4, S64, SP(ST_IM1), im1cl, 32);

    // ---- stage B (TH=8, R5 shapes) ----
    mconv_k<32, 1, 2, 4, 16><<<dim3(8, 8, 8), 256, 0, st>>>(im1cl, wp1a, b1a, A1, SP(ST_A1a), 64, 64, 64);
    apply(st, A1, 16, S32, SP(ST_A1a), A1cl, 32);
    mconv_k<32, 1, 1, 2, 16><<<dim3(4, 4, 16), 128, 0, st>>>(A1cl, wp1aa, b1aa, B1, SP(ST_B1a), 32, 32, 32);
    apply(st, B1, 16, S32, SP(ST_B1a), B1cl, 32);
    mconv_k<32, 1, 1, 2, 16><<<dim3(4, 4, 16), 128, 0, st>>>(B1cl, wp1b, b1b, c11, SP(ST_C11), 32, 32, 32);
    apply(st, c11, 16, S32, SP(ST_C11), c11cl, 32);
    mconv_k<32, 1, 2, 4, 16><<<dim3(8, 8, 8), 256, 0, st>>>(im2cl, wp1a, b1a, A1, SP(ST_A1b), 64, 64, 64);
    apply(st, A1, 16, S32, SP(ST_A1b), A1cl, 32);
    mconv_k<32, 1, 1, 2, 16><<<dim3(4, 4, 16), 128, 0, st>>>(A1cl, wp1aa, b1aa, B1, SP(ST_B1b), 32, 32, 32);
    apply(st, B1, 16, S32, SP(ST_B1b), B1cl, 32);
    mconv_k<32, 1, 1, 2, 16><<<dim3(4, 4, 16), 128, 0, st>>>(B1cl, wp1b, b1b, c21, SP(ST_C21), 32, 32, 32);
    apply(st, c21, 16, S32, SP(ST_C21), c21cl, 32);

    // ---- stage C ----
    mconv_k<32, 2, 2, 4, 32><<<dim3(4, 4, 4), 256, 0, st>>>(c11cl, wp2a, b2a, A2, SP(ST_A2a), 32, 32, 32);
    apply(st, A2, 32, S16, SP(ST_A2a), A2cl, 32);
    mconv_k<32, 2, 1, 2, 32><<<dim3(2, 2, 8), 128, 0, st>>>(A2cl, wp2aa, b2aa, B2, SP(ST_B2a), 16, 16, 16);
    apply(st, B2, 32, S16, SP(ST_B2a), B2cl, 32);
    mconv_k<32, 2, 1, 2, 32><<<dim3(2, 2, 8), 128, 0, st>>>(B2cl, wp2b, b2b, c12o, SP(ST_C12), 16, 16, 16);
    apply(st, c12o, 32, S16, SP(ST_C12), c12cl, 32);
    mconv_k<32, 2, 2, 4, 32><<<dim3(4, 4, 4), 256, 0, st>>>(c21cl, wp2a, b2a, A2, SP(ST_A2b), 32, 32, 32);
    apply(st, A2, 32, S16, SP(ST_A2b), A2cl, 32);
    mconv_k<32, 2, 1, 2, 32><<<dim3(2, 2, 8), 128, 0, st>>>(A2cl, wp2aa, b2aa, B2, SP(ST_B2b), 16, 16, 16);
    apply(st, B2, 32, S16, SP(ST_B2b), B2cl, 32);
    mconv_k<32, 2, 1, 2, 32><<<dim3(2, 2, 8), 128, 0, st>>>(B2cl, wp2b, b2b, c22o, SP(ST_C22), 16, 16, 16);
    apply(st, c22o, 32, S16, SP(ST_C22), c22cl, 32);

    costvolw_k<32, 128, 0><<<DIVUP(S16, 4), 256, 0, st>>>(c12o, c22o, cv2cl, 16, 16, 16);
    mconv_k<128, 2, 1, 2, 32><<<dim3(2, 2, 8), 128, 0, st>>>(cv2cl, wp20, b20, x20, SP(ST_X20), 16, 16, 16);
    apply(st, x20, 32, S16, SP(ST_X20), x20cl, 32);
    mconv_k<32, 1, 1, 2, 3><<<dim3(2, 2, 8), 128, 0, st>>>(x20cl, wpf2, bpf2, flow2, nullptr, 16, 16, 16);
    dctn_k<3><<<DIVUP(8 * S16, 256), 256, 0, st>>>(flow2, wt_d2, bd2, upflow2, x147cl, 141, 160, 16);
    dctn_k<32><<<DIVUP(8 * S16, 256), 256, 0, st>>>(x20, wt_uf2, buf2, nullptr, x147cl, 144, 160, 16);

    // ---- stage D ----
    warp_k<<<DIVUP(S32, 256), 256, 0, st>>>(c21, upflow2, warp1, 16, 32, 32, 32);
    costvolw_k<16, 160, 1><<<DIVUP(S32, 4), 256, 0, st>>>(c11, warp1, x147cl, 32, 32, 32);
    mconv_k<160, 2, 1, 2, 32><<<dim3(4, 4, 16), 128, 0, st>>>(x147cl, wp10, b10, x10, SP(ST_X10), 32, 32, 32);
    apply(st, x10, 32, S32, SP(ST_X10), x10cl, 32);
    mconv_k<32, 1, 1, 2, 3><<<dim3(4, 4, 16), 128, 0, st>>>(x10cl, wpf1, bpf1, flow1, nullptr, 32, 32, 32);
    dctn_k<3><<<DIVUP(8 * S32, 256), 256, 0, st>>>(flow1, wt_d1, bd1, upflow1, x196cl, 129, 224, 32);
    mdeconv_k<4><<<dim3(4, 4, 64), 256, 0, st>>>(x10cl, wpd_uf1, buf1, x196cl, 132, 224, 32);

    // ---- stage E ----
    warp_k<<<DIVUP(S64, 256), 256, 0, st>>>(im2, upflow1, warp0, 4, 64, 64, 64);
    costvolw_k<4, 224, 1><<<DIVUP(S64, 4), 256, 0, st>>>(im1, warp0, x196cl, 64, 64, 64);
    mconv_k<224, 2, 1, 4, 32><<<dim3(8, 8, 16), 256, 0, st>>>(x196cl, wp00, b00, x00, SP(ST_X00), 64, 64, 64);
    apply(st, x00, 32, S64, SP(ST_X00), x00cl, 32);
    mconv_k<32, 1, 1, 4, 3><<<dim3(8, 8, 16), 256, 0, st>>>(x00cl, wpf0, bpf0, flow0, nullptr, 64, 64, 64);
    dctn_k<3><<<DIVUP(S128, 256), 256, 0, st>>>(flow0, wt_d0, bd0, outF, nullptr, 0, 0, 64);
}

// Round 9
// 1135.260 us; speedup vs baseline: 1.6548x; 1.0559x over previous
//
#include <hip/hip_runtime.h>
#include <cstddef>
#include <cstdint>

#define DIVUP(a,b) (((a)+(b)-1)/(b))

typedef __attribute__((ext_vector_type(8))) short short8;
typedef __attribute__((ext_vector_type(4))) float f32x4;

__device__ __forceinline__ ushort f2bf(float f) {
    union { float f; uint32_t u; } v; v.f = f;
    uint32_t r = v.u + 0x7fffu + ((v.u >> 16) & 1u);
    return (ushort)(r >> 16);
}

// ============ fp32 direct conv (Cin=1 stride-2 encoder), batched, fused stats ======
template<int COUT, int STRIDE>
__global__ __launch_bounds__(256)
void conv3x3_k(const float* __restrict__ in0, const float* __restrict__ in1,
               const float* __restrict__ wgt, const float* __restrict__ bias,
               float* __restrict__ out, float* __restrict__ stats,
               int Cin, int D, int H, int W, int nz, long out_bs, int st_bs)
{
    constexpr int TD = 4, TH = 8, TW = 8;
    constexpr int ID = 2 * TD + 1, IH = 2 * TH + 1, IW = 2 * TW + 1;
    __shared__ float tile[ID * IH * IW];
    const int b = blockIdx.z / nz, zb = blockIdx.z % nz;
    const float* in = b ? in1 : in0;
    out += (long)b * out_bs;
    if (stats) stats += 2 * st_bs * b;
    const int Do = D / STRIDE, Ho = H / STRIDE, Wo = W / STRIDE;
    const int tid = threadIdx.x;
    const int tw = tid & 7, th = (tid >> 3) & 7, td = tid >> 6;
    const int ow0 = blockIdx.x * TW, oh0 = blockIdx.y * TH, od0 = zb * TD;
    const int iw0 = ow0 * STRIDE - 1, ih0 = oh0 * STRIDE - 1, id0 = od0 * STRIDE - 1;
    const size_t HWs = (size_t)H * W;

    float acc[COUT];
#pragma unroll
    for (int i = 0; i < COUT; i++) acc[i] = 0.f;

    for (int c = 0; c < Cin; ++c) {
        const float* inc = in + (size_t)c * D * HWs;
        for (int i = tid; i < ID * IH * IW; i += 256) {
            int lw = i % IW, lh = (i / IW) % IH, ld = i / (IW * IH);
            int gw = iw0 + lw, gh = ih0 + lh, gd = id0 + ld;
            float v = 0.f;
            if ((unsigned)gw < (unsigned)W && (unsigned)gh < (unsigned)H &&
                (unsigned)gd < (unsigned)D)
                v = inc[(size_t)gd * HWs + (size_t)gh * W + gw];
            tile[i] = v;
        }
        __syncthreads();
        float r[27];
        const int bd = td * STRIDE, bh = th * STRIDE, bw = tw * STRIDE;
#pragma unroll
        for (int kd = 0; kd < 3; kd++)
#pragma unroll
            for (int kh = 0; kh < 3; kh++)
#pragma unroll
                for (int kw = 0; kw < 3; kw++)
                    r[kd * 9 + kh * 3 + kw] =
                        tile[(bd + kd) * (IH * IW) + (bh + kh) * IW + (bw + kw)];
#pragma unroll
        for (int oc = 0; oc < COUT; ++oc) {
            const float* wp = wgt + ((size_t)oc * Cin + c) * 27;
            float s = 0.f;
#pragma unroll
            for (int t = 0; t < 27; t++) s = fmaf(wp[t], r[t], s);
            acc[oc] += s;
        }
        __syncthreads();
    }
    const size_t So = (size_t)Do * Ho * Wo;
    const size_t sp = (size_t)(od0 + td) * Ho * Wo + (size_t)(oh0 + th) * Wo + (ow0 + tw);
#pragma unroll
    for (int oc = 0; oc < COUT; ++oc)
        out[(size_t)oc * So + sp] = acc[oc] + bias[oc];

    if (stats) {
        __syncthreads();
        float* sm = tile;
        const int wv = tid >> 6, l = tid & 63;
#pragma unroll
        for (int oc = 0; oc < COUT; ++oc) {
            float sv = acc[oc] + bias[oc];
            float sq = sv * sv;
#pragma unroll
            for (int o = 32; o > 0; o >>= 1) {
                sv += __shfl_down(sv, o, 64);
                sq += __shfl_down(sq, o, 64);
            }
            if (l == 0) { sm[(wv * COUT + oc) * 2] = sv; sm[(wv * COUT + oc) * 2 + 1] = sq; }
        }
        __syncthreads();
        if (tid < COUT) {
            float s = 0.f, s2 = 0.f;
#pragma unroll
            for (int w = 0; w < 4; ++w) {
                s += sm[(w * COUT + tid) * 2];
                s2 += sm[(w * COUT + tid) * 2 + 1];
            }
            atomicAdd(&stats[2 * tid], s);
            atomicAdd(&stats[2 * tid + 1], s2);
        }
    }
}

// ============ MFMA implicit-GEMM conv (TH=8, fused stats, batched) =================
// b = blockIdx.z / nz selects batch (shared weights); frozen W00 config otherwise.
template<int CP, int NF, int STRIDE, int MW, int COUTR>
__global__ __launch_bounds__(MW * 64)
void mconv_k(const ushort* __restrict__ xcl, const ushort* __restrict__ wp,
             const float* __restrict__ bias, float* __restrict__ outcf,
             float* __restrict__ stats, int D, int H, int W,
             int nz, long in_bs, long out_bs, int st_bs)
{
    constexpr int KC = CP / 32;
    constexpr int MF = (STRIDE == 1) ? 4 : 1;
    constexpr int TD = MW;
    constexpr int TWl = (STRIDE == 1) ? 8 : 4;
    constexpr int HD = (STRIDE == 1) ? TD + 2 : 2 * TD + 1;
    constexpr int HH = (STRIDE == 1) ? 10 : 9;
    constexpr int HWd = (STRIDE == 1) ? 10 : 9;
    constexpr int HALO = HD * HH * HWd;
    constexpr int NTH = MW * 64;
    constexpr int NIT = (HALO * 4 + NTH - 1) / NTH;
    __shared__ __align__(16) ushort lds[HALO * 40];

    const int tid = threadIdx.x;
    const int wv = tid >> 6, l = tid & 63;
    const int b = blockIdx.z / nz, zb = blockIdx.z % nz;
    xcl += (long)b * in_bs;
    outcf += (long)b * out_bs;
    if (stats) stats += 2 * st_bs * b;
    const int od0 = zb * TD, oh0 = blockIdx.y * ((STRIDE == 1) ? 8 : 4),
              ow0 = blockIdx.x * TWl;
    const int id0 = od0 * STRIDE - 1, ih0 = oh0 * STRIDE - 1, iw0 = ow0 * STRIDE - 1;

    f32x4 acc[MF][NF];
#pragma unroll
    for (int mf = 0; mf < MF; mf++)
#pragma unroll
        for (int nf = 0; nf < NF; nf++) acc[mf][nf] = f32x4{0.f, 0.f, 0.f, 0.f};

    uint4 v[NIT];
    auto stage = [&](int kc) {
#pragma unroll
        for (int it = 0; it < NIT; ++it) {
            int idx = it * NTH + tid;
            uint4 t = {0u, 0u, 0u, 0u};
            if (idx < HALO * 4) {
                int pt = idx >> 2, part = idx & 3;
                int lw = pt % HWd, lh = (pt / HWd) % HH, ld = pt / (HWd * HH);
                int gx = iw0 + lw, gy = ih0 + lh, gz = id0 + ld;
                if ((unsigned)gx < (unsigned)W && (unsigned)gy < (unsigned)H &&
                    (unsigned)gz < (unsigned)D)
                    t = *reinterpret_cast<const uint4*>(
                        xcl + ((size_t)((gz * H + gy) * W + gx)) * CP + kc * 32 + part * 8);
            }
            v[it] = t;
        }
    };

    stage(0);
    for (int kc = 0; kc < KC; ++kc) {
        if (kc) __syncthreads();
#pragma unroll
        for (int it = 0; it < NIT; ++it) {
            int idx = it * NTH + tid;
            if (idx < HALO * 4)
                *reinterpret_cast<uint4*>(&lds[(idx >> 2) * 40 + (idx & 3) * 8]) = v[it];
        }
        __syncthreads();
        if (kc + 1 < KC) stage(kc + 1);
        if constexpr (STRIDE == 1) {
#pragma unroll
            for (int kd = 0; kd < 3; ++kd) {
#pragma unroll
                for (int kw = 0; kw < 3; ++kw) {
                    short8 af[9];
#pragma unroll
                    for (int r = 0; r < 9; ++r)
                        af[r] = *reinterpret_cast<const short8*>(
                            &lds[((wv + kd) * (HH * HWd) +
                                  (r + ((l >> 3) & 1)) * HWd + (l & 7) + kw) * 40 +
                                 ((l >> 4) << 3)]);
#pragma unroll
                    for (int kh = 0; kh < 3; ++kh) {
                        const int t = kd * 9 + kh * 3 + kw;
                        short8 bf[NF];
#pragma unroll
                        for (int nf = 0; nf < NF; ++nf)
                            bf[nf] = *reinterpret_cast<const short8*>(
                                wp + (((size_t)(t * KC + kc) * NF + nf) << 9) + (l << 3));
#pragma unroll
                        for (int mf = 0; mf < MF; ++mf)
#pragma unroll
                            for (int nf = 0; nf < NF; ++nf)
                                acc[mf][nf] = __builtin_amdgcn_mfma_f32_16x16x32_bf16(
                                    af[2 * mf + kh], bf[nf], acc[mf][nf], 0, 0, 0);
                    }
                }
            }
        } else {
#pragma unroll
            for (int t = 0; t < 27; ++t) {
                const int kd = t / 9, kh = (t / 3) % 3, kw = t % 3;
                short8 bf[NF];
#pragma unroll
                for (int nf = 0; nf < NF; ++nf)
                    bf[nf] = *reinterpret_cast<const short8*>(
                        wp + (((size_t)(t * KC + kc) * NF + nf) << 9) + (l << 3));
                int bw = l & 3, bh = (l >> 2) & 3;
                int p_loc = (2 * wv + kd) * (HH * HWd) + (2 * bh + kh) * HWd + (2 * bw + kw);
                short8 afs = *reinterpret_cast<const short8*>(&lds[p_loc * 40 + ((l >> 4) << 3)]);
#pragma unroll
                for (int nf = 0; nf < NF; ++nf)
                    acc[0][nf] = __builtin_amdgcn_mfma_f32_16x16x32_bf16(
                        afs, bf[nf], acc[0][nf], 0, 0, 0);
            }
        }
    }
    const int Do = D / STRIDE, Ho = H / STRIDE, Wo = W / STRIDE;
    const size_t So = (size_t)Do * Ho * Wo;
    float ps[NF], ps2[NF];
#pragma unroll
    for (int nf = 0; nf < NF; ++nf) { ps[nf] = 0.f; ps2[nf] = 0.f; }
#pragma unroll
    for (int nf = 0; nf < NF; ++nf) {
        int oc = nf * 16 + (l & 15);
        float bv = (oc < COUTR) ? bias[oc] : 0.f;
#pragma unroll
        for (int mf = 0; mf < MF; ++mf) {
#pragma unroll
            for (int r = 0; r < 4; ++r) {
                int q = ((l >> 4) << 2) + r;
                int bw, bh;
                if (STRIDE == 1) { bw = q & 7; bh = 2 * mf + (q >> 3); }
                else             { bw = q & 3; bh = (q >> 2) & 3; }
                int p = ((od0 + wv) * Ho + (oh0 + bh)) * Wo + (ow0 + bw);
                float val = acc[mf][nf][r] + bv;
                if (oc < COUTR) {
                    outcf[(size_t)oc * So + p] = val;
                    ps[nf] += val; ps2[nf] = fmaf(val, val, ps2[nf]);
                }
            }
        }
    }
    if (stats) {
        __syncthreads();
        float* sm = (float*)lds;
#pragma unroll
        for (int nf = 0; nf < NF; ++nf) {
            float s = ps[nf], s2 = ps2[nf];
            s += __shfl_down(s, 32, 64);  s2 += __shfl_down(s2, 32, 64);
            s += __shfl_down(s, 16, 64);  s2 += __shfl_down(s2, 16, 64);
            if (l < 16) {
                sm[((wv * NF + nf) * 16 + l) * 2] = s;
                sm[((wv * NF + nf) * 16 + l) * 2 + 1] = s2;
            }
        }
        __syncthreads();
        if (tid < NF * 16) {
            int nf = tid >> 4, c = tid & 15, oc = nf * 16 + c;
            if (oc < COUTR) {
                float s = 0.f, s2 = 0.f;
#pragma unroll
                for (int w = 0; w < MW; ++w) {
                    s += sm[((w * NF + nf) * 16 + c) * 2];
                    s2 += sm[((w * NF + nf) * 16 + c) * 2 + 1];
                }
                atomicAdd(&stats[2 * oc], s);
                atomicAdd(&stats[2 * oc + 1], s2);
            }
        }
    }
}

// ======================= consolidated weight prep ============================
struct WTask { const float* src; void* dst; int kind, Cin, COUT, KC, coutr, base; };
struct WTab { WTask t[17]; int n; };

__global__ __launch_bounds__(256)
void wprep_k(WTab tab)
{
    int b = blockIdx.x, ti = 0;
    for (int i = 0; i < tab.n; ++i) if (b >= tab.t[i].base) ti = i;
    const WTask tk = tab.t[ti];
    int idx = (b - tk.base) * 256 + threadIdx.x;
    if (tk.kind == 0) {
        int NF = tk.COUT >> 4;
        int tot = 27 * tk.KC * NF * 512;
        if (idx >= tot) return;
        int j = idx & 7, l = (idx >> 3) & 63;
        int g = idx >> 9;
        int nf = g % NF; g /= NF;
        int kc = g % tk.KC; int t = g / tk.KC;
        int oc = nf * 16 + (l & 15);
        int c = kc * 32 + ((l >> 4) << 3) + j;
        float v = (c < tk.Cin && oc < tk.coutr)
                      ? tk.src[((size_t)oc * tk.Cin + c) * 27 + t] : 0.f;
        ((ushort*)tk.dst)[idx] = f2bf(v);
    } else if (tk.kind == 1) {
        int NF = tk.KC;
        int tot = 8 * 8 * NF * 512;
        if (idx >= tot) return;
        int j = idx & 7, l = (idx >> 3) & 63;
        int g = idx >> 9;
        int nf = g % NF; g /= NF;
        int t = g % 8; int pp = g / 8;
        int oc = nf * 16 + (l & 15);
        int c = ((l >> 4) << 3) + j;
        int kd_ = (t >> 2) & 1, kh_ = (t >> 1) & 1, kw_ = t & 1;
        int pd = (pp >> 2) & 1, ph = (pp >> 1) & 1, pw = pp & 1;
        int kd = 3 - pd - 2 * kd_, kh = 3 - ph - 2 * kh_, kw = 3 - pw - 2 * kw_;
        float v = (oc < tk.COUT)
                      ? tk.src[(size_t)(c * tk.COUT + oc) * 64 + kd * 16 + kh * 4 + kw] : 0.f;
        ((ushort*)tk.dst)[idx] = f2bf(v);
    } else {
        int tot = tk.Cin * tk.COUT * 64;
        if (idx >= tot) return;
        int k = idx & 63; int oc = (idx >> 6) % tk.COUT; int c = (idx >> 6) / tk.COUT;
        ((float*)tk.dst)[((size_t)c * 64 + k) * tk.COUT + oc] = tk.src[idx];
    }
}

// ======================= MFMA deconv (uf1) =======================
template<int NF>
__global__ __launch_bounds__(256)
void mdeconv_k(const ushort* __restrict__ xcl, const ushort* __restrict__ wpd,
               const float* __restrict__ bias, ushort* __restrict__ outcl,
               int c0, int CPo, int Si)
{
    constexpr int HD = 5, HH = 9, HWd = 9, HALO = HD * HH * HWd;
    __shared__ __align__(16) ushort lds[HALO * 40];
    const int tid = threadIdx.x, wv = tid >> 6, l = tid & 63;
    const int pp = blockIdx.z & 7, tz = blockIdx.z >> 3;
    const int pd = (pp >> 2) & 1, ph = (pp >> 1) & 1, pw = pp & 1;
    const int oz0 = tz * 4, oy0 = blockIdx.y * 8, ox0 = blockIdx.x * 8;
    const int iz0 = oz0 + pd - 1, iy0 = oy0 + ph - 1, ix0 = ox0 + pw - 1;

    for (int idx = tid; idx < HALO * 4; idx += 256) {
        int pt = idx >> 2, part = idx & 3;
        int lw = pt % HWd, lh = (pt / HWd) % HH, ld = pt / (HWd * HH);
        int gx = ix0 + lw, gy = iy0 + lh, gz = iz0 + ld;
        uint4 t = {0u, 0u, 0u, 0u};
        if ((unsigned)gx < (unsigned)Si && (unsigned)gy < (unsigned)Si &&
            (unsigned)gz < (unsigned)Si)
            t = *reinterpret_cast<const uint4*>(
                xcl + ((size_t)((gz * Si + gy) * Si + gx)) * 32 + part * 8);
        *reinterpret_cast<uint4*>(&lds[pt * 40 + part * 8]) = t;
    }
    __syncthreads();

    f32x4 acc[4][NF];
#pragma unroll
    for (int mf = 0; mf < 4; mf++)
#pragma unroll
        for (int nf = 0; nf < NF; nf++) acc[mf][nf] = f32x4{0.f, 0.f, 0.f, 0.f};

#pragma unroll
    for (int kd = 0; kd < 2; ++kd) {
#pragma unroll
        for (int kw = 0; kw < 2; ++kw) {
            short8 af[8];
#pragma unroll
            for (int r = 0; r < 8; ++r)
                af[r] = *reinterpret_cast<const short8*>(
                    &lds[((wv + kd) * (HH * HWd) + (r + ((l >> 3) & 1)) * HWd +
                          (l & 7) + kw) * 40 + ((l >> 4) << 3)]);
#pragma unroll
            for (int kh = 0; kh < 2; ++kh) {
                const int t = kd * 4 + kh * 2 + kw;
                short8 bf[NF];
#pragma unroll
                for (int nf = 0; nf < NF; ++nf)
                    bf[nf] = *reinterpret_cast<const short8*>(
                        wpd + (((size_t)(pp * 8 + t) * NF + nf) << 9) + (l << 3));
#pragma unroll
                for (int mf = 0; mf < 4; ++mf)
#pragma unroll
                    for (int nf = 0; nf < NF; ++nf)
                        acc[mf][nf] = __builtin_amdgcn_mfma_f32_16x16x32_bf16(
                            af[2 * mf + kh], bf[nf], acc[mf][nf], 0, 0, 0);
            }
        }
    }
    const int Do = 2 * Si;
#pragma unroll
    for (int nf = 0; nf < NF; ++nf) {
        int oc = nf * 16 + (l & 15);
        float bv = bias[oc];
#pragma unroll
        for (int mf = 0; mf < 4; ++mf) {
#pragma unroll
            for (int r = 0; r < 4; ++r) {
                int q = ((l >> 4) << 2) + r;
                int bw = q & 7, bh = 2 * mf + (q >> 3);
                int oD = 2 * (oz0 + wv) + pd, oH = 2 * (oy0 + bh) + ph, oW = 2 * (ox0 + bw) + pw;
                outcl[(size_t)((oD * Do + oH) * Do + oW) * CPo + c0 + oc] =
                    f2bf(acc[mf][nf][r] + bv);
            }
        }
    }
}

// ======================= output-centric small deconv (COUT=3) ====
template<int CIN>
__global__ __launch_bounds__(256)
void dctn_k(const float* __restrict__ in, const float* __restrict__ wt,
            const float* __restrict__ bias, float* __restrict__ outcf,
            ushort* __restrict__ outcl, int c0, int CPo, int Si)
{
    const int Do = 2 * Si;
    const size_t So = (size_t)Do * Do * Do, ni = (size_t)Si * Si * Si;
    size_t p = (size_t)blockIdx.x * 256 + threadIdx.x;
    if (p >= So) return;
    int oxW = (int)(p % Do), oyH = (int)((p / Do) % Do), ozD = (int)(p / ((size_t)Do * Do));
    int pw = oxW & 1, ph = oyH & 1, pd = ozD & 1;
    int xb = oxW >> 1, yb = oyH >> 1, zb = ozD >> 1;
    float acc[3] = {0.f, 0.f, 0.f};
    for (int c = 0; c < CIN; ++c) {
        const float* inc = in + (size_t)c * ni;
        const float* wc = wt + (size_t)c * 64 * 3;
#pragma unroll
        for (int jd = 0; jd < 2; jd++) {
            int iz = zb + pd - jd; if ((unsigned)iz >= (unsigned)Si) continue;
            int kd = 1 - pd + 2 * jd;
#pragma unroll
            for (int jh = 0; jh < 2; jh++) {
                int iy = yb + ph - jh; if ((unsigned)iy >= (unsigned)Si) continue;
                int kh = 1 - ph + 2 * jh;
#pragma unroll
                for (int jw = 0; jw < 2; jw++) {
                    int ix = xb + pw - jw; if ((unsigned)ix >= (unsigned)Si) continue;
                    int kw = 1 - pw + 2 * jw;
                    float v = inc[((size_t)iz * Si + iy) * Si + ix];
                    const float* wr = wc + (size_t)((kd * 4 + kh) * 4 + kw) * 3;
                    acc[0] = fmaf(wr[0], v, acc[0]);
                    acc[1] = fmaf(wr[1], v, acc[1]);
                    acc[2] = fmaf(wr[2], v, acc[2]);
                }
            }
        }
    }
#pragma unroll
    for (int oc = 0; oc < 3; ++oc) {
        float o = acc[oc] + bias[oc];
        if (outcf) outcf[(size_t)oc * So + p] = o;
        if (outcl) outcl[p * CPo + c0 + oc] = f2bf(o);
    }
}

// ============ instance norm apply (batched ycl via Cper) =======================
__global__ __launch_bounds__(256)
void inorm_apply_k(const float* __restrict__ x, const float* __restrict__ stats,
                   float* __restrict__ y, size_t S, float invS,
                   ushort* __restrict__ ycl, int CP, int Cper, long ycl_bs)
{
    int c = blockIdx.y;
    float sum = stats[2 * c], ss = stats[2 * c + 1];
    float m = sum * invS;
    float r = rsqrtf(fmaxf(ss * invS - m * m, 0.f) + 1e-5f);
    size_t i = (size_t)blockIdx.x * 256 + threadIdx.x;
    if (i >= S) return;
    float v = (x[(size_t)c * S + i] - m) * r;
    v = v >= 0.f ? v : 0.1f * v;
    y[(size_t)c * S + i] = v;
    if (ycl) {
        int b = c / Cper, cl = c - b * Cper;
        ycl[(long)b * ycl_bs + (long)i * CP + cl] = f2bf(v);
    }
}

// ======================= cost volume + fused f1-channel copy =========
template<int C, int CP, int COPYC>
__global__ __launch_bounds__(256)
void costvolw_k(const float* __restrict__ f1, const float* __restrict__ f2,
                ushort* __restrict__ outcl, int D, int H, int W)
{
    const size_t S = (size_t)D * H * W;
    size_t p = (size_t)blockIdx.x * 4 + (threadIdx.x >> 6);
    if (p >= S) return;
    const int l = threadIdx.x & 63;
    int x = (int)(p % W); int y = (int)((p / W) % H); int z = (int)(p / ((size_t)W * H));
    float a[C];
#pragma unroll
    for (int c = 0; c < C; c++) a[c] = f1[(size_t)c * S + p];
    const float inv = 1.f / C;
    ushort* op = outcl + p * CP;
#pragma unroll
    for (int rep = 0; rep < 2; rep++) {
        int s = l + rep * 64;
        if (s < 125) {
            int v = s / 25 - 2, h = (s / 5) % 5 - 2, d = s % 5 - 2;
            int zz = z + v, yy = y + h, xx = x + d;
            float acc = 0.f;
            if ((unsigned)zz < (unsigned)D && (unsigned)yy < (unsigned)H &&
                (unsigned)xx < (unsigned)W) {
                size_t q = ((size_t)zz * H + yy) * (size_t)W + xx;
#pragma unroll
                for (int c = 0; c < C; c++) acc = fmaf(a[c], f2[(size_t)c * S + q], acc);
            }
            acc *= inv;
            op[s] = f2bf(acc >= 0.f ? acc : 0.1f * acc);
        }
    }
    if (COPYC && l < C)
        op[125 + l] = f2bf(f1[(size_t)l * S + p]);
}

// ======================= trilinear warp (clamped) =======================
__global__ __launch_bounds__(256)
void warp_k(const float* __restrict__ img, const float* __restrict__ flow,
            float* __restrict__ out, int C, int D, int H, int W)
{
    const size_t S = (size_t)D * H * W;
    size_t p = (size_t)blockIdx.x * 256 + threadIdx.x;
    if (p >= S) return;
    int x = (int)(p % W); int y = (int)((p / W) % H); int z = (int)(p / ((size_t)W * H));
    float cd = fminf(fmaxf((float)z + flow[p], 0.f), (float)(D - 1));
    float ch = fminf(fmaxf((float)y + flow[S + p], 0.f), (float)(H - 1));
    float cw = fminf(fmaxf((float)x + flow[2 * S + p], 0.f), (float)(W - 1));
    int d0 = (int)cd, h0 = (int)ch, w0 = (int)cw;
    float fd = cd - d0, fh = ch - h0, fw = cw - w0;
    int d1 = min(d0 + 1, D - 1), h1 = min(h0 + 1, H - 1), w1 = min(w0 + 1, W - 1);
    size_t i000 = ((size_t)d0 * H + h0) * W + w0, i001 = ((size_t)d0 * H + h0) * W + w1;
    size_t i010 = ((size_t)d0 * H + h1) * W + w0, i011 = ((size_t)d0 * H + h1) * W + w1;
    size_t i100 = ((size_t)d1 * H + h0) * W + w0, i101 = ((size_t)d1 * H + h0) * W + w1;
    size_t i110 = ((size_t)d1 * H + h1) * W + w0, i111 = ((size_t)d1 * H + h1) * W + w1;
    float w000 = (1 - fd) * (1 - fh) * (1 - fw), w001 = (1 - fd) * (1 - fh) * fw;
    float w010 = (1 - fd) * fh * (1 - fw),       w011 = (1 - fd) * fh * fw;
    float w100 = fd * (1 - fh) * (1 - fw),       w101 = fd * (1 - fh) * fw;
    float w110 = fd * fh * (1 - fw),             w111 = fd * fh * fw;
    for (int c = 0; c < C; c++) {
        const float* ic = img + (size_t)c * S;
        float v = w000 * ic[i000] + w001 * ic[i001] + w010 * ic[i010] + w011 * ic[i011]
                + w100 * ic[i100] + w101 * ic[i101] + w110 * ic[i110] + w111 * ic[i111];
        out[(size_t)c * S + p] = v;
    }
}

// ======================= host orchestration =======================
static void apply(hipStream_t st, float* x, int C, size_t S, const float* stats,
                  ushort* ycl, int CP, int Cper, long ycl_bs)
{
    dim3 g((unsigned)DIVUP(S, 256), C);
    inorm_apply_k<<<g, 256, 0, st>>>(x, stats, x, S, 1.0f / (float)S, ycl, CP, Cper, ycl_bs);
}

extern "C" void kernel_launch(void* const* d_in, const int* in_sizes, int n_in,
                              void* d_out, int out_size, void* d_ws, size_t ws_size,
                              hipStream_t st)
{
    (void)in_sizes; (void)n_in; (void)out_size; (void)ws_size;
    const float* atlas  = (const float*)d_in[0];
    const float* target = (const float*)d_in[1];
    const float *W_ct = (const float*)d_in[2],  *b_ct = (const float*)d_in[3];
    const float *W1a  = (const float*)d_in[4],  *b1a  = (const float*)d_in[5];
    const float *W1aa = (const float*)d_in[6],  *b1aa = (const float*)d_in[7];
    const float *W1b  = (const float*)d_in[8],  *b1b  = (const float*)d_in[9];
    const float *W2a  = (const float*)d_in[10], *b2a  = (const float*)d_in[11];
    const float *W2aa = (const float*)d_in[12], *b2aa = (const float*)d_in[13];
    const float *W2b  = (const float*)d_in[14], *b2b  = (const float*)d_in[15];
    const float *W20  = (const float*)d_in[16], *b20  = (const float*)d_in[17];
    const float *Wpf2 = (const float*)d_in[18], *bpf2 = (const float*)d_in[19];
    const float *Wd2  = (const float*)d_in[20], *bd2  = (const float*)d_in[21];
    const float *Wuf2 = (const float*)d_in[22], *buf2 = (const float*)d_in[23];
    const float *W10  = (const float*)d_in[24], *b10  = (const float*)d_in[25];
    const float *Wpf1 = (const float*)d_in[26], *bpf1 = (const float*)d_in[27];
    const float *Wd1  = (const float*)d_in[28], *bd1  = (const float*)d_in[29];
    const float *Wuf1 = (const float*)d_in[30], *buf1 = (const float*)d_in[31];
    const float *W00  = (const float*)d_in[32], *b00  = (const float*)d_in[33];
    const float *Wpf0 = (const float*)d_in[34], *bpf0 = (const float*)d_in[35];
    const float *Wd0  = (const float*)d_in[36], *bd0  = (const float*)d_in[37];

    const size_t S128 = 128u * 128 * 128, S64 = 64u * 64 * 64, S32 = 32u * 32 * 32, S16 = 16u * 16 * 16;

    char* base = (char*)d_ws;
    size_t off = 0;
    auto AF = [&](size_t n) { off = (off + 255) & ~(size_t)255; float* p = (float*)(base + off); off += n * 4; return p; };
    auto AH = [&](size_t n) { off = (off + 255) & ~(size_t)255; ushort* p = (ushort*)(base + off); off += n * 2; return p; };

    ushort* wp1a  = AH(13824);  ushort* wp1aa = AH(13824); ushort* wp1b = AH(13824);
    ushort* wp2a  = AH(27648);  ushort* wp2aa = AH(27648); ushort* wp2b = AH(27648);
    ushort* wp20  = AH(110592); ushort* wp10 = AH(138240); ushort* wp00 = AH(193536);
    ushort* wpf2  = AH(13824);  ushort* wpf1 = AH(13824);  ushort* wpf0 = AH(13824);
    ushort* wpd_uf1 = AH(131072);
    float* wt_uf2 = AF(6144);
    float* wt_d2  = AF(576);    float* wt_d1 = AF(576);    float* wt_d0 = AF(576);
    float* stats = AF(1024);
    float* im12 = AF(8 * S64);
    float* im1 = im12; float* im2 = im12 + 4 * S64;
    float* A1   = AF(32 * S32); ushort* A1cl = AH(2 * S32 * 32);
    float* B1   = AF(32 * S32); ushort* B1cl = AH(2 * S32 * 32);
    float* c1121 = AF(32 * S32); ushort* c1121cl = AH(2 * S32 * 32);
    float* c11 = c1121; float* c21 = c1121 + 16 * S32;
    ushort* c11cl = c1121cl; ushort* c21cl = c1121cl + S32 * 32;
    float* A2   = AF(64 * S16); ushort* A2cl = AH(2 * S16 * 32);
    float* B2   = AF(64 * S16); ushort* B2cl = AH(2 * S16 * 32);
    ushort* cv2cl = AH(S16 * 128);
    float* x20  = AF(32 * S16); ushort* x20cl = AH(S16 * 32);
    float* flow2 = AF(3 * S16); float* upflow2 = AF(3 * S32);
    float* warp1 = AF(16 * S32);
    ushort* x147cl = AH(S32 * 160);
    float* x10  = AF(32 * S32); ushort* x10cl = AH(S32 * 32);
    float* flow1 = AF(3 * S32); float* upflow1 = AF(3 * S64);
    float* warp0 = AF(4 * S64);
    ushort* x196cl = AH(S64 * 224);
    float* x00  = AF(32 * S64); float* flow0 = AF(3 * S64);

    ushort* im12cl = x196cl;           // [2][S64][32] overlay, dead after stage B
    ushort* x00cl = x196cl;            // live only after W00 consumed x196cl

    float* outF = (float*)d_out;
    float* c22o = outF + 3 * S128;
    float* c12o = c22o + 32 * S16;

    // stats layout: batched pairs contiguous
    const int ST_IM=0, ST_A1=8, ST_B1=40, ST_C1=72, ST_A2=104, ST_B2=168, ST_C2=232,
              ST_X20=296, ST_X10=328, ST_X00=360;
    auto SP = [&](int o) { return stats + 2 * o; };
    hipMemsetAsync(stats, 0, 4096, st);

    WTab tab; int nb = 0, ti = 0;
    auto addw = [&](const float* s, void* d, int kind, int Cin, int COUT, int KC, int coutr) {
        int tot = (kind == 0) ? 27 * KC * (COUT >> 4) * 512
                 : (kind == 1) ? 8 * 8 * KC * 512 : Cin * COUT * 64;
        tab.t[ti] = WTask{s, d, kind, Cin, COUT, KC, coutr, nb};
        nb += DIVUP(tot, 256); ti++;
    };
    addw(W1a,  wp1a,  0,  4, 16, 1, 16);
    addw(W1aa, wp1aa, 0, 16, 16, 1, 16);
    addw(W1b,  wp1b,  0, 16, 16, 1, 16);
    addw(W2a,  wp2a,  0, 16, 32, 1, 32);
    addw(W2aa, wp2aa, 0, 32, 32, 1, 32);
    addw(W2b,  wp2b,  0, 32, 32, 1, 32);
    addw(W20,  wp20,  0, 125, 32, 4, 32);
    addw(W10,  wp10,  0, 147, 32, 5, 32);
    addw(W00,  wp00,  0, 196, 32, 7, 32);
    addw(Wpf2, wpf2,  0, 32, 16, 1, 3);
    addw(Wpf1, wpf1,  0, 32, 16, 1, 3);
    addw(Wpf0, wpf0,  0, 32, 16, 1, 3);
    addw(Wuf1, wpd_uf1, 1, 32, 64, 4, 64);
    addw(Wuf2, wt_uf2, 2, 32, 3, 0, 3);
    addw(Wd2,  wt_d2,  2, 3, 3, 0, 3);
    addw(Wd1,  wt_d1,  2, 3, 3, 0, 3);
    addw(Wd0,  wt_d0,  2, 3, 3, 0, 3);
    tab.n = ti;
    wprep_k<<<nb, 256, 0, st>>>(tab);

    // ---- stage A (batched: b0=target->im1, b1=atlas->im2) ----
    conv3x3_k<4, 2><<<dim3(8, 8, 32), 256, 0, st>>>(target, atlas, W_ct, b_ct, im12,
                                                    SP(ST_IM), 1, 128, 128, 128,
                                                    16, (long)(4 * S64), 4);
    apply(st, im12, 8, S64, SP(ST_IM), im12cl, 32, 4, (long)(32 * S64));

    // ---- stage B (batched) ----
    mconv_k<32, 1, 2, 4, 16><<<dim3(8, 8, 16), 256, 0, st>>>(im12cl, wp1a, b1a, A1, SP(ST_A1),
        64, 64, 64, 8, (long)(32 * S64), (long)(16 * S32), 16);
    apply(st, A1, 32, S32, SP(ST_A1), A1cl, 32, 16, (long)(S32 * 32));
    mconv_k<32, 1, 1, 2, 16><<<dim3(4, 4, 32), 128, 0, st>>>(A1cl, wp1aa, b1aa, B1, SP(ST_B1),
        32, 32, 32, 16, (long)(S32 * 32), (long)(16 * S32), 16);
    apply(st, B1, 32, S32, SP(ST_B1), B1cl, 32, 16, (long)(S32 * 32));
    mconv_k<32, 1, 1, 2, 16><<<dim3(4, 4, 32), 128, 0, st>>>(B1cl, wp1b, b1b, c1121, SP(ST_C1),
        32, 32, 32, 16, (long)(S32 * 32), (long)(16 * S32), 16);
    apply(st, c1121, 32, S32, SP(ST_C1), c1121cl, 32, 16, (long)(S32 * 32));

    // ---- stage C (batched) ----
    mconv_k<32, 2, 2, 4, 32><<<dim3(4, 4, 8), 256, 0, st>>>(c1121cl, wp2a, b2a, A2, SP(ST_A2),
        32, 32, 32, 4, (long)(S32 * 32), (long)(32 * S16), 32);
    apply(st, A2, 64, S16, SP(ST_A2), A2cl, 32, 32, (long)(S16 * 32));
    mconv_k<32, 2, 1, 2, 32><<<dim3(2, 2, 16), 128, 0, st>>>(A2cl, wp2aa, b2aa, B2, SP(ST_B2),
        16, 16, 16, 8, (long)(S16 * 32), (long)(32 * S16), 32);
    apply(st, B2, 64, S16, SP(ST_B2), B2cl, 32, 32, (long)(S16 * 32));
    mconv_k<32, 2, 1, 2, 32><<<dim3(2, 2, 16), 128, 0, st>>>(B2cl, wp2b, b2b, c12o, SP(ST_C2),
        16, 16, 16, 8, (long)(S16 * 32), (long)(c22o - c12o), 32);
    apply(st, c12o, 32, S16, SP(ST_C2), nullptr, 0, 32, 0);
    apply(st, c22o, 32, S16, SP(ST_C2 + 32), nullptr, 0, 32, 0);

    costvolw_k<32, 128, 0><<<DIVUP(S16, 4), 256, 0, st>>>(c12o, c22o, cv2cl, 16, 16, 16);
    mconv_k<128, 2, 1, 2, 32><<<dim3(2, 2, 8), 128, 0, st>>>(cv2cl, wp20, b20, x20, SP(ST_X20),
        16, 16, 16, 8, 0, 0, 0);
    apply(st, x20, 32, S16, SP(ST_X20), x20cl, 32, 32, 0);
    mconv_k<32, 1, 1, 2, 3><<<dim3(2, 2, 8), 128, 0, st>>>(x20cl, wpf2, bpf2, flow2, nullptr,
        16, 16, 16, 8, 0, 0, 0);
    dctn_k<3><<<DIVUP(8 * S16, 256), 256, 0, st>>>(flow2, wt_d2, bd2, upflow2, x147cl, 141, 160, 16);
    dctn_k<32><<<DIVUP(8 * S16, 256), 256, 0, st>>>(x20, wt_uf2, buf2, nullptr, x147cl, 144, 160, 16);

    // ---- stage D ----
    warp_k<<<DIVUP(S32, 256), 256, 0, st>>>(c21, upflow2, warp1, 16, 32, 32, 32);
    costvolw_k<16, 160, 1><<<DIVUP(S32, 4), 256, 0, st>>>(c11, warp1, x147cl, 32, 32, 32);
    mconv_k<160, 2, 1, 2, 32><<<dim3(4, 4, 16), 128, 0, st>>>(x147cl, wp10, b10, x10, SP(ST_X10),
        32, 32, 32, 16, 0, 0, 0);
    apply(st, x10, 32, S32, SP(ST_X10), x10cl, 32, 32, 0);
    mconv_k<32, 1, 1, 2, 3><<<dim3(4, 4, 16), 128, 0, st>>>(x10cl, wpf1, bpf1, flow1, nullptr,
        32, 32, 32, 16, 0, 0, 0);
    dctn_k<3><<<DIVUP(8 * S32, 256), 256, 0, st>>>(flow1, wt_d1, bd1, upflow1, x196cl, 129, 224, 32);
    mdeconv_k<4><<<dim3(4, 4, 64), 256, 0, st>>>(x10cl, wpd_uf1, buf1, x196cl, 132, 224, 32);

    // ---- stage E ----
    warp_k<<<DIVUP(S64, 256), 256, 0, st>>>(im2, upflow1, warp0, 4, 64, 64, 64);
    costvolw_k<4, 224, 1><<<DIVUP(S64, 4), 256, 0, st>>>(im1, warp0, x196cl, 64, 64, 64);
    mconv_k<224, 2, 1, 4, 32><<<dim3(8, 8, 16), 256, 0, st>>>(x196cl, wp00, b00, x00, SP(ST_X00),
        64, 64, 64, 16, 0, 0, 0);
    apply(st, x00, 32, S64, SP(ST_X00), x00cl, 32, 32, 0);
    mconv_k<32, 1, 1, 4, 3><<<dim3(8, 8, 16), 256, 0, st>>>(x00cl, wpf0, bpf0, flow0, nullptr,
        64, 64, 64, 16, 0, 0, 0);
    dctn_k<3><<<DIVUP(S128, 256), 256, 0, st>>>(flow0, wt_d0, bd0, outF, nullptr, 0, 0, 64);
}